// Round 10
// baseline (2355.279 us; speedup 1.0000x reference)
//
#include <hip/hip_runtime.h>
#include <hip/hip_bf16.h>

// GIN_34789235098229 — round 20: LDS-act MLP (no shuffles, no register arrays).
// Round 19 = 2345us CATASTROPHE: FETCH 361MB + WRITE 737MB/dispatch = register
// arrays spilled to scratch (partial unroll -> runtime-indexed zc/y arrays).
// Round-16 mlp (68.5us) is LDS-INSTR bound: 54cy LDS vs 32cy VALU per k-wave,
// x4 SIMDs sharing one LDS unit => model 70us == measured. Fix: stage acts in
// LDS k-major ([k][node], pad 129 => conflict-free broadcast b32 reads), block
// 2 nodes/thread so each weight float4 feeds 2 FMAs: per k = 2 b32 + 4 b128
// (~60cy LDS) vs 64cy VALU => balanced. Acts/y round-trip LDS in exact fp32,
// ascending-k FMA order => bit-identical mlp outputs. No shfl, no indexed reg
// arrays => no spill path. LDS 66.3KB, 2 blocks/CU. Model: ~38us.
// Free rider: pool l==3 writes out directly; finalize = gpool tail only.

typedef unsigned short ushort_t;
typedef unsigned int uint_t;

#define NN 100000
#define EE 3200000
#define GG 512
#define NBK 391    // ceil(NN/256); bucket = node >> 8
#define NHB 256    // histogram blocks
#define ECHUNK 12500  // EE / NHB exactly
#define MLPBLOCKS 782        // ceil(100000 / 128 nodes-per-block)
#define NWAVE (MLPBLOCKS * 4)  // 3128 wave slots for stats partials

// ---------- detection ----------
__global__ __launch_bounds__(256) void detect_kernel(
    const uint_t* __restrict__ xw, const uint_t* __restrict__ ew,
    const uint_t* __restrict__ bw, int* __restrict__ flags)
{
    __shared__ int sb[256], se[256], sbb[256];
    int t = threadIdx.x;
    uint_t w = xw[t];
    uint_t eL = (w >> 7) & 0xffu;
    sb[t] = (eL >= 112u && eL <= 135u) ? 1 : 0;
    se[t] = (ew[2 * t + 1] == 0u) ? 1 : 0;
    sbb[t] = (bw[NN - 512 + 2 * t + 1] == 0u) ? 1 : 0;
    __syncthreads();
    for (int off = 128; off > 0; off >>= 1) {
        if (t < off) { sb[t] += sb[t + off]; se[t] += se[t + off]; sbb[t] += sbb[t + off]; }
        __syncthreads();
    }
    if (t == 0) {
        flags[0] = (sb[0] < 128) ? 1 : 0;   // 1 => fp32 floats
        flags[1] = (se[0] >= 128) ? 1 : 0;  // 1 => int64 edges
        flags[2] = (sbb[0] >= 128) ? 1 : 0; // 1 => int64 batch
    }
}

// ---------- canonicalization ----------
__global__ __launch_bounds__(256) void cvt_w_kernel(
    const void* __restrict__ W1, const void* __restrict__ b1,
    const void* __restrict__ W2, const void* __restrict__ b2,
    const void* __restrict__ g, const void* __restrict__ be,
    const int* __restrict__ flags, float* __restrict__ wf)
{
    int i = blockIdx.x * 256 + threadIdx.x;
    if (i >= 33792) return;
    const void* src; int off;
    if (i < 16384)      { src = W1; off = i; }
    else if (i < 32768) { src = W2; off = i - 16384; }
    else if (i < 33024) { src = b1; off = i - 32768; }
    else if (i < 33280) { src = b2; off = i - 33024; }
    else if (i < 33536) { src = g;  off = i - 33280; }
    else                { src = be; off = i - 33536; }
    float v = flags[0] ? ((const float*)src)[off]
                       : __bfloat162float(((const __hip_bfloat16*)src)[off]);
    wf[i] = v;
}

__global__ __launch_bounds__(256) void cvt_x_kernel(
    const void* __restrict__ x, const int* __restrict__ flags,
    float* __restrict__ zA, ushort_t* __restrict__ zb, int total)
{
    int i = blockIdx.x * 256 + threadIdx.x;
    if (i >= total) return;
    float v;
    ushort_t bits;
    if (flags[0]) {
        v = ((const float*)x)[i];
        __hip_bfloat16 b = __float2bfloat16(v);
        bits = *(ushort_t*)&b;
    } else {
        bits = ((const ushort_t*)x)[i];
        uint_t u = (uint_t)bits << 16;
        v = __uint_as_float(u);
    }
    zA[i] = v;
    zb[i] = bits;
}

// batch is SORTED: zero-atomic group offsets via boundary detection.
// gstart[g] (G+1 entries) = first index i with batch[i] >= g.
__global__ __launch_bounds__(256) void cvt_batch_kernel(
    const int* __restrict__ bw, const int* __restrict__ flags,
    int* __restrict__ b32, int* __restrict__ gstart, int n)
{
    int i = blockIdx.x * 256 + threadIdx.x;
    if (i >= n) return;
    int i64 = flags[2];
    int v = i64 ? bw[2 * i] : bw[i];
    b32[i] = v;
    int vn = (i + 1 < n) ? (i64 ? bw[2 * (i + 1)] : bw[i + 1]) : GG;
    if (i == 0) {
        for (int g = 0; g <= v; ++g) gstart[g] = 0;
    }
    if (vn != v) {
        for (int g = v + 1; g <= vn; ++g) gstart[g] = i + 1;
    }
}

// ---------- atomic-free CSR build (round 9, unchanged) ----------
__global__ __launch_bounds__(256) void count_hist_kernel(
    const int* __restrict__ ei, const int* __restrict__ flags,
    int* __restrict__ histo, int E)
{
    __shared__ int lh[NBK];
    int b = blockIdx.x, t = threadIdx.x;
    for (int j = t; j < NBK; j += 256) lh[j] = 0;
    __syncthreads();
    int i64 = flags[1];
    int e0 = b * ECHUNK, e1 = min(e0 + ECHUNK, E);
    for (int i = e0 + t; i < e1; i += 256) {
        int d = i64 ? ei[2 * (E + i)] : ei[E + i];
        atomicAdd(&lh[d >> 8], 1);
    }
    __syncthreads();
    for (int j = t; j < NBK; j += 256) histo[j * NHB + b] = lh[j];
}

__global__ __launch_bounds__(NHB) void blockscan_kernel(
    int* __restrict__ histo, int* __restrict__ tot)
{
    __shared__ int sd[NHB];
    int j = blockIdx.x, t = threadIdx.x;
    int v = histo[j * NHB + t];
    sd[t] = v;
    __syncthreads();
    #pragma unroll
    for (int off = 1; off < NHB; off <<= 1) {
        int add = (t >= off) ? sd[t - off] : 0;
        __syncthreads();
        sd[t] += add;
        __syncthreads();
    }
    histo[j * NHB + t] = sd[t] - v;
    if (t == NHB - 1) tot[j] = sd[NHB - 1];
}

__global__ __launch_bounds__(512) void bscan_kernel(
    const int* __restrict__ tot, int* __restrict__ bktoff)
{
    __shared__ int sd[512];
    int t = threadIdx.x;
    int v = (t < NBK) ? tot[t] : 0;
    sd[t] = v;
    __syncthreads();
    #pragma unroll
    for (int off = 1; off < 512; off <<= 1) {
        int add = (t >= off) ? sd[t - off] : 0;
        __syncthreads();
        sd[t] += add;
        __syncthreads();
    }
    if (t < NBK) bktoff[t] = sd[t] - v;
    if (t == 511) bktoff[NBK] = sd[511];
}

__global__ __launch_bounds__(256) void pair_scatter_kernel(
    const int* __restrict__ ei, const int* __restrict__ flags,
    const int* __restrict__ histo, const int* __restrict__ bktoff,
    int2* __restrict__ pairs, int E)
{
    __shared__ int cur[NBK];
    int b = blockIdx.x, t = threadIdx.x;
    for (int j = t; j < NBK; j += 256) cur[j] = histo[j * NHB + b] + bktoff[j];
    __syncthreads();
    int i64 = flags[1];
    int e0 = b * ECHUNK, e1 = min(e0 + ECHUNK, E);
    for (int i = e0 + t; i < e1; i += 256) {
        int d = i64 ? ei[2 * (E + i)] : ei[E + i];
        int s = i64 ? ei[2 * i]       : ei[i];
        int p = atomicAdd(&cur[d >> 8], 1);
        pairs[p] = make_int2(d, s);
    }
}

__global__ __launch_bounds__(256) void bucket_deg_kernel(
    const int2* __restrict__ pairs, const int* __restrict__ bktoff,
    int* __restrict__ deg, int N)
{
    __shared__ int cnt[256];
    int j = blockIdx.x, t = threadIdx.x;
    cnt[t] = 0;
    __syncthreads();
    int e0 = bktoff[j], e1 = bktoff[j + 1];
    for (int i = e0 + t; i < e1; i += 256)
        atomicAdd(&cnt[pairs[i].x & 255], 1);
    __syncthreads();
    int idx = j * 256 + t;
    if (idx < N) deg[idx] = cnt[t];
}

__global__ __launch_bounds__(256) void scan1_kernel(
    const int* __restrict__ deg, int* __restrict__ part, int* __restrict__ bsum, int n)
{
    __shared__ int sd[256];
    int t = threadIdx.x;
    int i0 = blockIdx.x * 1024 + t * 4;
    int v0 = 0, v1 = 0, v2 = 0, v3 = 0;
    if (i0 + 3 < n) {
        int4 v = *(const int4*)(deg + i0);
        v0 = v.x; v1 = v.y; v2 = v.z; v3 = v.w;
    } else if (i0 < n) {
        v0 = deg[i0];
        if (i0 + 1 < n) v1 = deg[i0 + 1];
        if (i0 + 2 < n) v2 = deg[i0 + 2];
    }
    int s = v0 + v1 + v2 + v3;
    sd[t] = s;
    __syncthreads();
    #pragma unroll
    for (int off = 1; off < 256; off <<= 1) {
        int add = (t >= off) ? sd[t - off] : 0;
        __syncthreads();
        sd[t] += add;
        __syncthreads();
    }
    int incl = sd[t];
    int e0 = incl - s;
    int p0 = e0 + v0, p1 = p0 + v1, p2 = p1 + v2, p3 = p2 + v3;
    if (i0 < n)     part[i0]     = p0;
    if (i0 + 1 < n) part[i0 + 1] = p1;
    if (i0 + 2 < n) part[i0 + 2] = p2;
    if (i0 + 3 < n) part[i0 + 3] = p3;
    if (t == 255) bsum[blockIdx.x] = incl;
}

__global__ __launch_bounds__(128) void scan2_kernel(int* __restrict__ bsum, int nb)
{
    __shared__ int sd[128];
    int t = threadIdx.x;
    int own = (t < nb) ? bsum[t] : 0;
    sd[t] = own;
    __syncthreads();
    #pragma unroll
    for (int off = 1; off < 128; off <<= 1) {
        int add = (t >= off) ? sd[t - off] : 0;
        __syncthreads();
        sd[t] += add;
        __syncthreads();
    }
    if (t < nb) bsum[t] = sd[t] - own;
}

__global__ __launch_bounds__(256) void scan3_kernel(
    const int* __restrict__ part, const int* __restrict__ bsum,
    const int* __restrict__ deg, int* __restrict__ indptr,
    float* __restrict__ inv_deg, int n)
{
    int i = blockIdx.x * 256 + threadIdx.x;
    if (i >= n) return;
    int val = part[i] + bsum[i >> 10];
    indptr[i + 1] = val;
    int d = deg[i];
    inv_deg[i] = (d > 0) ? 1.0f / (float)d : 0.0f;
    if (i == 0) indptr[0] = 0;
}

// invg from sorted-boundary gstart + identity-init of ac slot 0 (A=1, C=0)
__global__ __launch_bounds__(512) void invg_kernel(
    const int* __restrict__ gstart, float* __restrict__ invg,
    float* __restrict__ ac, int G)
{
    int g = threadIdx.x;
    if (g < G) {
        int c = gstart[g + 1] - gstart[g];
        invg[g] = (c > 0) ? 1.0f / (float)c : 0.0f;
    }
    if (g < 64) ac[g] = 1.0f;
    else if (g < 128) ac[g] = 0.0f;
}

__global__ __launch_bounds__(256) void csr_fill_kernel(
    const int2* __restrict__ pairs, const int* __restrict__ bktoff,
    const int* __restrict__ indptr, int* __restrict__ esrc, int N)
{
    __shared__ int cur[256];
    int j = blockIdx.x, t = threadIdx.x;
    int idx = j * 256 + t;
    cur[t] = (idx < N) ? indptr[idx] : 0;
    __syncthreads();
    int e0 = bktoff[j], e1 = bktoff[j + 1];
    for (int i = e0 + t; i < e1; i += 256) {
        int2 e = pairs[i];
        int p = atomicAdd(&cur[e.x & 255], 1);
        esrc[p] = e.y;
    }
}

// ---------- per-layer ----------
// agg: edge-index broadcast, explicit 16-deep gather batches (round-14 form).
// zout = A*(z_own + mean(z_nb)) + C*(1+[deg>0]); A,C from the ac slot.
__global__ __launch_bounds__(256) void agg_kernel(
    const float* __restrict__ zprev, const ushort_t* __restrict__ zb,
    const int* __restrict__ indptr, const int* __restrict__ esrc,
    const float* __restrict__ inv_deg, const float* __restrict__ ac,
    float* __restrict__ zout, int n)
{
    int t = threadIdx.x;
    int grp = t >> 4, l = t & 15;
    int lane = t & 63;
    int gl0 = lane & 48;
    int node = blockIdx.x * 16 + grp;
    if (node >= n) return;
    int e0 = indptr[node], e1 = indptr[node + 1];
    // hoisted independent loads: overlap with the gather loop
    float idg = inv_deg[node];
    float4 own = *(const float4*)(zprev + (size_t)node * 64 + l * 4);
    float4 A = *(const float4*)(ac + l * 4);
    float4 C = *(const float4*)(ac + 64 + l * 4);
    float a0 = 0.f, a1 = 0.f, a2 = 0.f, a3 = 0.f;
    const ushort_t* zbl = zb + l * 4;

    int base = e0;
    // full chunks: 16 gathers batched (issue loop separate from accumulate)
    for (; base + 16 <= e1; base += 16) {
        int myi = esrc[base + l];
        uint2 vv[16];
        #pragma unroll
        for (int j = 0; j < 16; ++j) {
            int s = __shfl(myi, gl0 + j, 64);
            vv[j] = *(const uint2*)(zbl + (size_t)s * 64);
        }
        #pragma unroll
        for (int j = 0; j < 16; ++j) {
            a0 += __uint_as_float(vv[j].x << 16);
            a1 += __uint_as_float(vv[j].x & 0xffff0000u);
            a2 += __uint_as_float(vv[j].y << 16);
            a3 += __uint_as_float(vv[j].y & 0xffff0000u);
        }
    }
    // remainder: masked 16-wide batch; pad lanes re-read edge-0's row (L1 hit)
    // and are forced to +0.0f => accumulation chain is bit-identical.
    int cnt = e1 - base;
    if (cnt > 0) {
        int myi = (l < cnt) ? esrc[base + l] : 0;
        uint2 vv[16];
        #pragma unroll
        for (int j = 0; j < 16; ++j) {
            int jj = (j < cnt) ? j : 0;
            int s = __shfl(myi, gl0 + jj, 64);
            uint2 v = *(const uint2*)(zbl + (size_t)s * 64);
            vv[j].x = (j < cnt) ? v.x : 0u;
            vv[j].y = (j < cnt) ? v.y : 0u;
        }
        #pragma unroll
        for (int j = 0; j < 16; ++j) {
            a0 += __uint_as_float(vv[j].x << 16);
            a1 += __uint_as_float(vv[j].x & 0xffff0000u);
            a2 += __uint_as_float(vv[j].y << 16);
            a3 += __uint_as_float(vv[j].y & 0xffff0000u);
        }
    }

    float cf = (idg > 0.f) ? 2.f : 1.f;
    float4 r;
    r.x = fmaf(A.x, fmaf(idg, a0, own.x), C.x * cf);
    r.y = fmaf(A.y, fmaf(idg, a1, own.y), C.y * cf);
    r.z = fmaf(A.z, fmaf(idg, a2, own.z), C.z * cf);
    r.w = fmaf(A.w, fmaf(idg, a3, own.w), C.w * cf);
    *(float4*)(zout + (size_t)node * 64 + l * 4) = r;
}

// MLP round 20: acts + weights in LDS; 2 nodes/thread, 16 features each.
// zs is [k][node] with 129-float rows: broadcast act reads are conflict-free
// ((k*129+n)%32 = (k+n)%32; the 16 distinct even/odd n hit 16 distinct banks).
// No shuffles, no runtime-indexed register arrays => no spill path.
// FMA order ascending k per output == bit-identical mlp outputs.
__global__ __launch_bounds__(256, 2) void mlp_kernel(
    float* __restrict__ zf, ushort_t* __restrict__ zb,
    const float* __restrict__ W1f, const float* __restrict__ b1f,
    const float* __restrict__ W2f, const float* __restrict__ b2f,
    float* __restrict__ partials, int n)
{
    __shared__ float w1s[4096];
    __shared__ float w2s[4096];
    __shared__ float bs[128];
    __shared__ float zs[64 * 129];   // [k][node], 33024 B
    int t = threadIdx.x;
    for (int i = t; i < 4096; i += 256) {
        w1s[i] = W1f[i];
        w2s[i] = W2f[i];
    }
    if (t < 64) bs[t] = b1f[t];
    else if (t < 128) bs[t] = b2f[t - 64];

    // stage acts transposed: coalesced float4 read, scattered b32 LDS writes
    int base = blockIdx.x * 128;
    for (int i = t; i < 2048; i += 256) {    // 2048 float4 = 128 nodes x 16
        int node = i >> 4;
        int k4 = (i & 15) * 4;
        int gn = base + node;
        float4 v = (gn < n) ? *(const float4*)(zf + (size_t)gn * 64 + k4)
                            : make_float4(0.f, 0.f, 0.f, 0.f);
        zs[(k4    ) * 129 + node] = v.x;
        zs[(k4 + 1) * 129 + node] = v.y;
        zs[(k4 + 2) * 129 + node] = v.z;
        zs[(k4 + 3) * 129 + node] = v.w;
    }
    __syncthreads();

    int sub = t & 3;
    int lane = t & 63;
    int j0 = sub * 16;
    int n0l = (t >> 2) * 2, n1l = n0l + 1;   // local node pair
    int node0 = base + n0l, node1 = base + n1l;
    bool v0 = node0 < n, v1 = node1 < n;

    // GEMM1: y for both nodes; each weight float4 feeds 2 FMuls
    float y0[16], y1[16];
    #pragma unroll
    for (int q = 0; q < 16; ++q) { y0[q] = bs[j0 + q]; y1[q] = bs[j0 + q]; }
    #pragma unroll
    for (int k = 0; k < 64; ++k) {
        float a0 = zs[k * 129 + n0l];
        float a1 = zs[k * 129 + n1l];
        const float4* w = (const float4*)(w1s + k * 64 + j0);
        #pragma unroll
        for (int q = 0; q < 4; ++q) {
            float4 wv = w[q];
            y0[4*q]   = fmaf(a0, wv.x, y0[4*q]);
            y0[4*q+1] = fmaf(a0, wv.y, y0[4*q+1]);
            y0[4*q+2] = fmaf(a0, wv.z, y0[4*q+2]);
            y0[4*q+3] = fmaf(a0, wv.w, y0[4*q+3]);
            y1[4*q]   = fmaf(a1, wv.x, y1[4*q]);
            y1[4*q+1] = fmaf(a1, wv.y, y1[4*q+1]);
            y1[4*q+2] = fmaf(a1, wv.z, y1[4*q+2]);
            y1[4*q+3] = fmaf(a1, wv.w, y1[4*q+3]);
        }
    }
    #pragma unroll
    for (int q = 0; q < 16; ++q) {
        y0[q] = fmaxf(y0[q], 0.f);
        y1[q] = fmaxf(y1[q], 0.f);
    }
    __syncthreads();              // all act reads done; safe to overwrite zs
    #pragma unroll
    for (int q = 0; q < 16; ++q) {
        zs[(j0 + q) * 129 + n0l] = y0[q];
        zs[(j0 + q) * 129 + n1l] = y1[q];
    }
    __syncthreads();

    // GEMM2: o for both nodes, reading y from zs
    float o0[16], o1[16];
    #pragma unroll
    for (int q = 0; q < 16; ++q) { o0[q] = bs[64 + j0 + q]; o1[q] = bs[64 + j0 + q]; }
    #pragma unroll
    for (int k = 0; k < 64; ++k) {
        float a0 = zs[k * 129 + n0l];
        float a1 = zs[k * 129 + n1l];
        const float4* w = (const float4*)(w2s + k * 64 + j0);
        #pragma unroll
        for (int q = 0; q < 4; ++q) {
            float4 wv = w[q];
            o0[4*q]   = fmaf(a0, wv.x, o0[4*q]);
            o0[4*q+1] = fmaf(a0, wv.y, o0[4*q+1]);
            o0[4*q+2] = fmaf(a0, wv.z, o0[4*q+2]);
            o0[4*q+3] = fmaf(a0, wv.w, o0[4*q+3]);
            o1[4*q]   = fmaf(a1, wv.x, o1[4*q]);
            o1[4*q+1] = fmaf(a1, wv.y, o1[4*q+1]);
            o1[4*q+2] = fmaf(a1, wv.z, o1[4*q+2]);
            o1[4*q+3] = fmaf(a1, wv.w, o1[4*q+3]);
        }
    }
    #pragma unroll
    for (int q = 0; q < 16; ++q) {
        o0[q] = fmaxf(o0[q], 0.f);
        o1[q] = fmaxf(o1[q], 0.f);
    }

    // stores: fp32 + bf16 mirror, masked per node
    float* zrow0 = zf + (size_t)node0 * 64;
    float* zrow1 = zf + (size_t)node1 * 64;
    ushort_t* zbrow0 = zb + (size_t)node0 * 64;
    ushort_t* zbrow1 = zb + (size_t)node1 * 64;
    if (v0) {
        #pragma unroll
        for (int q = 0; q < 4; ++q) {
            float4 v;
            v.x = o0[4*q]; v.y = o0[4*q+1]; v.z = o0[4*q+2]; v.w = o0[4*q+3];
            *(float4*)(zrow0 + j0 + q * 4) = v;
            __hip_bfloat16 p0 = __float2bfloat16(v.x);
            __hip_bfloat16 p1 = __float2bfloat16(v.y);
            __hip_bfloat16 p2 = __float2bfloat16(v.z);
            __hip_bfloat16 p3 = __float2bfloat16(v.w);
            uint2 pw;
            pw.x = (uint_t)*(ushort_t*)&p0 | ((uint_t)*(ushort_t*)&p1 << 16);
            pw.y = (uint_t)*(ushort_t*)&p2 | ((uint_t)*(ushort_t*)&p3 << 16);
            *(uint2*)(zbrow0 + j0 + q * 4) = pw;
        }
    }
    if (v1) {
        #pragma unroll
        for (int q = 0; q < 4; ++q) {
            float4 v;
            v.x = o1[4*q]; v.y = o1[4*q+1]; v.z = o1[4*q+2]; v.w = o1[4*q+3];
            *(float4*)(zrow1 + j0 + q * 4) = v;
            __hip_bfloat16 p0 = __float2bfloat16(v.x);
            __hip_bfloat16 p1 = __float2bfloat16(v.y);
            __hip_bfloat16 p2 = __float2bfloat16(v.z);
            __hip_bfloat16 p3 = __float2bfloat16(v.w);
            uint2 pw;
            pw.x = (uint_t)*(ushort_t*)&p0 | ((uint_t)*(ushort_t*)&p1 << 16);
            pw.y = (uint_t)*(ushort_t*)&p2 | ((uint_t)*(ushort_t*)&p3 << 16);
            *(uint2*)(zbrow1 + j0 + q * 4) = pw;
        }
    }

    // fused BN stats: node-pair pre-sum, butterfly over the 16 lanes sharing
    // sub (strides 4..32), lanes 0..3 store per-wave partials (no atomics)
    float ss[16], qq[16];
    #pragma unroll
    for (int q = 0; q < 16; ++q) {
        float h0 = v0 ? o0[q] : 0.f;
        float h1 = v1 ? o1[q] : 0.f;
        ss[q] = h0 + h1;
        qq[q] = h0 * h0 + h1 * h1;
    }
    #pragma unroll
    for (int m = 4; m <= 32; m <<= 1) {
        #pragma unroll
        for (int q = 0; q < 16; ++q) {
            ss[q] += __shfl_xor(ss[q], m, 64);
            qq[q] += __shfl_xor(qq[q], m, 64);
        }
    }
    if ((lane >> 2) == 0) {
        int wid = (blockIdx.x * 256 + t) >> 6;
        #pragma unroll
        for (int q = 0; q < 16; ++q) {
            partials[(size_t)(j0 + q) * NWAVE + wid]      = ss[q];
            partials[(size_t)(64 + j0 + q) * NWAVE + wid] = qq[q];
        }
    }
}

// reduce per-wave partials -> BN affine (A,C) for this layer's ac slot.
__global__ __launch_bounds__(256) void redstats_kernel(
    const float* __restrict__ partials, const float* __restrict__ gammaf,
    const float* __restrict__ betaf, float* __restrict__ ac_out)
{
    __shared__ float s1[256], s2[256];
    int f = blockIdx.x;
    int t = threadIdx.x;
    const float* ph = partials + (size_t)f * NWAVE;
    const float* pq = partials + (size_t)(64 + f) * NWAVE;
    float a = 0.f, b = 0.f;
    for (int i = t; i < NWAVE; i += 256) { a += ph[i]; b += pq[i]; }
    s1[t] = a; s2[t] = b;
    __syncthreads();
    for (int off = 128; off > 0; off >>= 1) {
        if (t < off) { s1[t] += s1[t + off]; s2[t] += s2[t + off]; }
        __syncthreads();
    }
    if (t == 0) {
        const float invN = 1.0f / (float)NN;
        float mu = s1[0] * invN;
        float var = s2[0] * invN - mu * mu;
        if (var < 0.f) var = 0.f;
        float A = gammaf[f] * rsqrtf(var + 1e-5f);
        float C = betaf[f] - mu * A;
        ac_out[f] = A;
        ac_out[64 + f] = C;
    }
}

// pools: h = A*z + C; node_pool (+=) or (l==3) direct write to out;
// gpool run-length atomics.
__global__ __launch_bounds__(256) void pool_kernel(
    const float* __restrict__ z, float* __restrict__ node_pool,
    const int* __restrict__ b32, const float* __restrict__ ac,
    float* __restrict__ gpool, const int* __restrict__ flags,
    void* __restrict__ out, int N, int first, int last)
{
    int wave = (blockIdx.x * 256 + threadIdx.x) >> 6;
    int f = threadIdx.x & 63;
    int n0 = wave * 16;
    if (n0 >= N) return;
    int n1 = min(n0 + 16, N);
    float A = ac[f], C = ac[64 + f];
    int fp32 = flags[0];
    float racc = 0.f;
    int cur = b32[n0];
    int n = n0;
    for (; n + 4 <= n1; n += 4) {
        int4 gv = *(const int4*)(b32 + n);
        size_t idx = (size_t)n * 64 + f;
        float z0 = z[idx];
        float z1 = z[idx + 64];
        float z2 = z[idx + 128];
        float z3 = z[idx + 192];
        float h0 = fmaf(z0, A, C);
        float h1 = fmaf(z1, A, C);
        float h2 = fmaf(z2, A, C);
        float h3 = fmaf(z3, A, C);
        float p0, p1, p2, p3;
        if (first) {
            p0 = h0; p1 = h1; p2 = h2; p3 = h3;
        } else {
            p0 = node_pool[idx]       + h0;
            p1 = node_pool[idx + 64]  + h1;
            p2 = node_pool[idx + 128] + h2;
            p3 = node_pool[idx + 192] + h3;
        }
        if (last) {
            if (fp32) {
                ((float*)out)[idx]       = p0;
                ((float*)out)[idx + 64]  = p1;
                ((float*)out)[idx + 128] = p2;
                ((float*)out)[idx + 192] = p3;
            } else {
                __hip_bfloat16 b0 = __float2bfloat16(p0);
                __hip_bfloat16 b1 = __float2bfloat16(p1);
                __hip_bfloat16 b2 = __float2bfloat16(p2);
                __hip_bfloat16 b3 = __float2bfloat16(p3);
                ((__hip_bfloat16*)out)[idx]       = b0;
                ((__hip_bfloat16*)out)[idx + 64]  = b1;
                ((__hip_bfloat16*)out)[idx + 128] = b2;
                ((__hip_bfloat16*)out)[idx + 192] = b3;
            }
        } else {
            node_pool[idx]       = p0;
            node_pool[idx + 64]  = p1;
            node_pool[idx + 128] = p2;
            node_pool[idx + 192] = p3;
        }
        int gs0 = gv.x, gs1 = gv.y, gs2 = gv.z, gs3 = gv.w;
        if (gs0 != cur) { atomicAdd(&gpool[(size_t)cur * 64 + f], racc); racc = 0.f; cur = gs0; }
        racc += h0;
        if (gs1 != cur) { atomicAdd(&gpool[(size_t)cur * 64 + f], racc); racc = 0.f; cur = gs1; }
        racc += h1;
        if (gs2 != cur) { atomicAdd(&gpool[(size_t)cur * 64 + f], racc); racc = 0.f; cur = gs2; }
        racc += h2;
        if (gs3 != cur) { atomicAdd(&gpool[(size_t)cur * 64 + f], racc); racc = 0.f; cur = gs3; }
        racc += h3;
    }
    for (; n < n1; ++n) {  // tail (unused when 16 | N; kept for safety)
        int g = b32[n];
        if (g != cur) { atomicAdd(&gpool[(size_t)cur * 64 + f], racc); racc = 0.f; cur = g; }
        size_t idx = (size_t)n * 64 + f;
        float hv = fmaf(z[idx], A, C);
        float np = first ? hv : (node_pool[idx] + hv);
        if (last) {
            if (fp32) ((float*)out)[idx] = np;
            else ((__hip_bfloat16*)out)[idx] = __float2bfloat16(np);
        } else node_pool[idx] = np;
        racc += hv;
    }
    atomicAdd(&gpool[(size_t)cur * 64 + f], racc);
}

// finalize: gpool tail only (node section written by pool l==3)
__global__ __launch_bounds__(256) void finalize_kernel(
    const float* __restrict__ gpool, const float* __restrict__ invg,
    const int* __restrict__ flags, void* __restrict__ out, int N)
{
    int i = blockIdx.x * 256 + threadIdx.x;
    if (i >= GG * 64) return;
    float v = gpool[i] * invg[i >> 6];
    int nd = N * 64;
    if (flags[0]) ((float*)out)[nd + i] = v;
    else ((__hip_bfloat16*)out)[nd + i] = __float2bfloat16(v);
}

extern "C" void kernel_launch(void* const* d_in, const int* in_sizes, int n_in,
                              void* d_out, int out_size, void* d_ws, size_t ws_size,
                              hipStream_t stream)
{
    constexpr int N = NN, E = EE, G = GG;
    constexpr int ND = N * 64;

    const void* x     = d_in[0];
    const void* W1    = d_in[1];
    const void* b1    = d_in[2];
    const void* W2    = d_in[3];
    const void* b2    = d_in[4];
    const void* gamma = d_in[5];
    const void* beta  = d_in[6];
    const int* ei     = (const int*)d_in[7];
    const int* batw   = (const int*)d_in[8];

    char* p = (char*)d_ws;
    auto alloc = [&](size_t bytes) -> char* {
        char* r = p;
        p += (bytes + 255) & ~(size_t)255;
        return r;
    };
    float*    zbufA     = (float*)alloc((size_t)ND * 4);
    float*    zbufB     = (float*)alloc((size_t)ND * 4);
    float*    node_pool = (float*)alloc((size_t)ND * 4);
    ushort_t* zb        = (ushort_t*)alloc((size_t)ND * 2);
    int*      esrc      = (int*)alloc((size_t)E * 4);
    int*      indptr    = (int*)alloc((size_t)(N + 1) * 4);
    int*      deg       = (int*)alloc((size_t)N * 4);
    int*      part      = (int*)alloc((size_t)N * 4);
    float*    invdeg    = (float*)alloc((size_t)N * 4);
    int*      b32       = (int*)alloc((size_t)N * 4);
    int*      bsum      = (int*)alloc(128 * 4);
    int*      gstart    = (int*)alloc((size_t)(G + 1) * 4);
    float*    invg      = (float*)alloc(G * 4);
    float*    gpool     = (float*)alloc((size_t)G * 64 * 4);
    float*    ac5       = (float*)alloc(5 * 128 * 4);  // slot0 identity, slots1..4 BN_l
    float*    partials  = (float*)alloc((size_t)128 * NWAVE * 4);  // 1.6 MB
    float*    wf        = (float*)alloc(33792 * 4);
    int*      flags     = (int*)alloc(16 * 4);
    int*      histo     = (int*)alloc((size_t)NBK * NHB * 4);
    int*      tot       = (int*)alloc((size_t)NBK * 4);
    int*      bktoff    = (int*)alloc((size_t)(NBK + 1) * 4);
    // pairs aliases node_pool: dead until first pool_kernel; E*8 == ND*4 bytes
    int2*     pairs     = (int2*)node_pool;

    hipMemsetAsync(gpool, 0, (size_t)G * 64 * 4, stream);

    detect_kernel<<<1, 256, 0, stream>>>(
        (const uint_t*)x, (const uint_t*)ei, (const uint_t*)batw, flags);
    cvt_w_kernel<<<132, 256, 0, stream>>>(W1, b1, W2, b2, gamma, beta, flags, wf);
    cvt_x_kernel<<<(ND + 255) / 256, 256, 0, stream>>>(x, flags, zbufA, zb, ND);
    cvt_batch_kernel<<<(N + 255) / 256, 256, 0, stream>>>(batw, flags, b32, gstart, N);
    count_hist_kernel<<<NHB, 256, 0, stream>>>(ei, flags, histo, E);
    blockscan_kernel<<<NBK, NHB, 0, stream>>>(histo, tot);
    bscan_kernel<<<1, 512, 0, stream>>>(tot, bktoff);
    pair_scatter_kernel<<<NHB, 256, 0, stream>>>(ei, flags, histo, bktoff, pairs, E);
    bucket_deg_kernel<<<NBK, 256, 0, stream>>>(pairs, bktoff, deg, N);
    int nb = (N + 1023) / 1024;  // 98
    scan1_kernel<<<nb, 256, 0, stream>>>(deg, part, bsum, N);
    scan2_kernel<<<1, 128, 0, stream>>>(bsum, nb);
    scan3_kernel<<<(N + 255) / 256, 256, 0, stream>>>(part, bsum, deg, indptr, invdeg, N);
    invg_kernel<<<1, 512, 0, stream>>>(gstart, invg, ac5, G);
    csr_fill_kernel<<<NBK, 256, 0, stream>>>(pairs, bktoff, indptr, esrc, N);

    float* zin = zbufA;
    float* zout = zbufB;
    for (int l = 0; l < 4; ++l) {
        agg_kernel<<<(N + 15) / 16, 256, 0, stream>>>(
            zin, zb, indptr, esrc, invdeg, ac5 + l * 128, zout, N);
        mlp_kernel<<<MLPBLOCKS, 256, 0, stream>>>(
            zout, zb, wf + l * 4096, wf + 32768 + l * 64,
            wf + 16384 + l * 4096, wf + 33024 + l * 64,
            partials, N);
        redstats_kernel<<<64, 256, 0, stream>>>(
            partials, wf + 33280 + l * 64, wf + 33536 + l * 64,
            ac5 + (l + 1) * 128);
        pool_kernel<<<(N + 63) / 64, 256, 0, stream>>>(
            zout, node_pool, b32, ac5 + (l + 1) * 128, gpool, flags, d_out,
            N, (l == 0) ? 1 : 0, (l == 3) ? 1 : 0);
        float* tmp = zin; zin = zout; zout = tmp;
    }
    finalize_kernel<<<128, 256, 0, stream>>>(gpool, invg, flags, d_out, N);
}

// Round 12
// 765.432 us; speedup vs baseline: 3.0771x; 3.0771x over previous
//
#include <hip/hip_runtime.h>
#include <hip/hip_bf16.h>

// GIN_34789235098229 — round 21b: resubmit of round 21 (infra failure, no verdict).
// CONSOLIDATE. mlp reverted to round-16 exact (68.5us, known-good codegen).
// Rounds 17-20 post-mortem: hipcc will not allocate >128 VGPRs for this kernel
// shape — every mlp variant needing >~50 live floats/thread (reg-blocked or
// weight-stationary) spilled to scratch (FETCH 360MB + WRITE 736MB, VALU 5%).
// Round-20 stop rule fired: mlp is frozen at the round-16 form. Kept round-20's
// verified-correct free riders: pool l==3 writes h directly to out; finalize =
// 32k gpool tail only.

typedef unsigned short ushort_t;
typedef unsigned int uint_t;

#define NN 100000
#define EE 3200000
#define GG 512
#define NBK 391    // ceil(NN/256); bucket = node >> 8
#define NHB 256    // histogram blocks
#define ECHUNK 12500  // EE / NHB exactly
#define MLPGRID 1563   // ceil(NN*4/256)
#define NWAVE (MLPGRID * 4)  // 6252 wave slots for stats partials

// ---------- detection ----------
__global__ __launch_bounds__(256) void detect_kernel(
    const uint_t* __restrict__ xw, const uint_t* __restrict__ ew,
    const uint_t* __restrict__ bw, int* __restrict__ flags)
{
    __shared__ int sb[256], se[256], sbb[256];
    int t = threadIdx.x;
    uint_t w = xw[t];
    uint_t eL = (w >> 7) & 0xffu;
    sb[t] = (eL >= 112u && eL <= 135u) ? 1 : 0;
    se[t] = (ew[2 * t + 1] == 0u) ? 1 : 0;
    sbb[t] = (bw[NN - 512 + 2 * t + 1] == 0u) ? 1 : 0;
    __syncthreads();
    for (int off = 128; off > 0; off >>= 1) {
        if (t < off) { sb[t] += sb[t + off]; se[t] += se[t + off]; sbb[t] += sbb[t + off]; }
        __syncthreads();
    }
    if (t == 0) {
        flags[0] = (sb[0] < 128) ? 1 : 0;   // 1 => fp32 floats
        flags[1] = (se[0] >= 128) ? 1 : 0;  // 1 => int64 edges
        flags[2] = (sbb[0] >= 128) ? 1 : 0; // 1 => int64 batch
    }
}

// ---------- canonicalization ----------
__global__ __launch_bounds__(256) void cvt_w_kernel(
    const void* __restrict__ W1, const void* __restrict__ b1,
    const void* __restrict__ W2, const void* __restrict__ b2,
    const void* __restrict__ g, const void* __restrict__ be,
    const int* __restrict__ flags, float* __restrict__ wf)
{
    int i = blockIdx.x * 256 + threadIdx.x;
    if (i >= 33792) return;
    const void* src; int off;
    if (i < 16384)      { src = W1; off = i; }
    else if (i < 32768) { src = W2; off = i - 16384; }
    else if (i < 33024) { src = b1; off = i - 32768; }
    else if (i < 33280) { src = b2; off = i - 33024; }
    else if (i < 33536) { src = g;  off = i - 33280; }
    else                { src = be; off = i - 33536; }
    float v = flags[0] ? ((const float*)src)[off]
                       : __bfloat162float(((const __hip_bfloat16*)src)[off]);
    wf[i] = v;
}

__global__ __launch_bounds__(256) void cvt_x_kernel(
    const void* __restrict__ x, const int* __restrict__ flags,
    float* __restrict__ zA, ushort_t* __restrict__ zb, int total)
{
    int i = blockIdx.x * 256 + threadIdx.x;
    if (i >= total) return;
    float v;
    ushort_t bits;
    if (flags[0]) {
        v = ((const float*)x)[i];
        __hip_bfloat16 b = __float2bfloat16(v);
        bits = *(ushort_t*)&b;
    } else {
        bits = ((const ushort_t*)x)[i];
        uint_t u = (uint_t)bits << 16;
        v = __uint_as_float(u);
    }
    zA[i] = v;
    zb[i] = bits;
}

// batch is SORTED: zero-atomic group offsets via boundary detection.
// gstart[g] (G+1 entries) = first index i with batch[i] >= g.
__global__ __launch_bounds__(256) void cvt_batch_kernel(
    const int* __restrict__ bw, const int* __restrict__ flags,
    int* __restrict__ b32, int* __restrict__ gstart, int n)
{
    int i = blockIdx.x * 256 + threadIdx.x;
    if (i >= n) return;
    int i64 = flags[2];
    int v = i64 ? bw[2 * i] : bw[i];
    b32[i] = v;
    int vn = (i + 1 < n) ? (i64 ? bw[2 * (i + 1)] : bw[i + 1]) : GG;
    if (i == 0) {
        for (int g = 0; g <= v; ++g) gstart[g] = 0;
    }
    if (vn != v) {
        for (int g = v + 1; g <= vn; ++g) gstart[g] = i + 1;
    }
}

// ---------- atomic-free CSR build (round 9, unchanged) ----------
__global__ __launch_bounds__(256) void count_hist_kernel(
    const int* __restrict__ ei, const int* __restrict__ flags,
    int* __restrict__ histo, int E)
{
    __shared__ int lh[NBK];
    int b = blockIdx.x, t = threadIdx.x;
    for (int j = t; j < NBK; j += 256) lh[j] = 0;
    __syncthreads();
    int i64 = flags[1];
    int e0 = b * ECHUNK, e1 = min(e0 + ECHUNK, E);
    for (int i = e0 + t; i < e1; i += 256) {
        int d = i64 ? ei[2 * (E + i)] : ei[E + i];
        atomicAdd(&lh[d >> 8], 1);
    }
    __syncthreads();
    for (int j = t; j < NBK; j += 256) histo[j * NHB + b] = lh[j];
}

__global__ __launch_bounds__(NHB) void blockscan_kernel(
    int* __restrict__ histo, int* __restrict__ tot)
{
    __shared__ int sd[NHB];
    int j = blockIdx.x, t = threadIdx.x;
    int v = histo[j * NHB + t];
    sd[t] = v;
    __syncthreads();
    #pragma unroll
    for (int off = 1; off < NHB; off <<= 1) {
        int add = (t >= off) ? sd[t - off] : 0;
        __syncthreads();
        sd[t] += add;
        __syncthreads();
    }
    histo[j * NHB + t] = sd[t] - v;
    if (t == NHB - 1) tot[j] = sd[NHB - 1];
}

__global__ __launch_bounds__(512) void bscan_kernel(
    const int* __restrict__ tot, int* __restrict__ bktoff)
{
    __shared__ int sd[512];
    int t = threadIdx.x;
    int v = (t < NBK) ? tot[t] : 0;
    sd[t] = v;
    __syncthreads();
    #pragma unroll
    for (int off = 1; off < 512; off <<= 1) {
        int add = (t >= off) ? sd[t - off] : 0;
        __syncthreads();
        sd[t] += add;
        __syncthreads();
    }
    if (t < NBK) bktoff[t] = sd[t] - v;
    if (t == 511) bktoff[NBK] = sd[511];
}

__global__ __launch_bounds__(256) void pair_scatter_kernel(
    const int* __restrict__ ei, const int* __restrict__ flags,
    const int* __restrict__ histo, const int* __restrict__ bktoff,
    int2* __restrict__ pairs, int E)
{
    __shared__ int cur[NBK];
    int b = blockIdx.x, t = threadIdx.x;
    for (int j = t; j < NBK; j += 256) cur[j] = histo[j * NHB + b] + bktoff[j];
    __syncthreads();
    int i64 = flags[1];
    int e0 = b * ECHUNK, e1 = min(e0 + ECHUNK, E);
    for (int i = e0 + t; i < e1; i += 256) {
        int d = i64 ? ei[2 * (E + i)] : ei[E + i];
        int s = i64 ? ei[2 * i]       : ei[i];
        int p = atomicAdd(&cur[d >> 8], 1);
        pairs[p] = make_int2(d, s);
    }
}

__global__ __launch_bounds__(256) void bucket_deg_kernel(
    const int2* __restrict__ pairs, const int* __restrict__ bktoff,
    int* __restrict__ deg, int N)
{
    __shared__ int cnt[256];
    int j = blockIdx.x, t = threadIdx.x;
    cnt[t] = 0;
    __syncthreads();
    int e0 = bktoff[j], e1 = bktoff[j + 1];
    for (int i = e0 + t; i < e1; i += 256)
        atomicAdd(&cnt[pairs[i].x & 255], 1);
    __syncthreads();
    int idx = j * 256 + t;
    if (idx < N) deg[idx] = cnt[t];
}

__global__ __launch_bounds__(256) void scan1_kernel(
    const int* __restrict__ deg, int* __restrict__ part, int* __restrict__ bsum, int n)
{
    __shared__ int sd[256];
    int t = threadIdx.x;
    int i0 = blockIdx.x * 1024 + t * 4;
    int v0 = 0, v1 = 0, v2 = 0, v3 = 0;
    if (i0 + 3 < n) {
        int4 v = *(const int4*)(deg + i0);
        v0 = v.x; v1 = v.y; v2 = v.z; v3 = v.w;
    } else if (i0 < n) {
        v0 = deg[i0];
        if (i0 + 1 < n) v1 = deg[i0 + 1];
        if (i0 + 2 < n) v2 = deg[i0 + 2];
    }
    int s = v0 + v1 + v2 + v3;
    sd[t] = s;
    __syncthreads();
    #pragma unroll
    for (int off = 1; off < 256; off <<= 1) {
        int add = (t >= off) ? sd[t - off] : 0;
        __syncthreads();
        sd[t] += add;
        __syncthreads();
    }
    int incl = sd[t];
    int e0 = incl - s;
    int p0 = e0 + v0, p1 = p0 + v1, p2 = p1 + v2, p3 = p2 + v3;
    if (i0 < n)     part[i0]     = p0;
    if (i0 + 1 < n) part[i0 + 1] = p1;
    if (i0 + 2 < n) part[i0 + 2] = p2;
    if (i0 + 3 < n) part[i0 + 3] = p3;
    if (t == 255) bsum[blockIdx.x] = incl;
}

__global__ __launch_bounds__(128) void scan2_kernel(int* __restrict__ bsum, int nb)
{
    __shared__ int sd[128];
    int t = threadIdx.x;
    int own = (t < nb) ? bsum[t] : 0;
    sd[t] = own;
    __syncthreads();
    #pragma unroll
    for (int off = 1; off < 128; off <<= 1) {
        int add = (t >= off) ? sd[t - off] : 0;
        __syncthreads();
        sd[t] += add;
        __syncthreads();
    }
    if (t < nb) bsum[t] = sd[t] - own;
}

__global__ __launch_bounds__(256) void scan3_kernel(
    const int* __restrict__ part, const int* __restrict__ bsum,
    const int* __restrict__ deg, int* __restrict__ indptr,
    float* __restrict__ inv_deg, int n)
{
    int i = blockIdx.x * 256 + threadIdx.x;
    if (i >= n) return;
    int val = part[i] + bsum[i >> 10];
    indptr[i + 1] = val;
    int d = deg[i];
    inv_deg[i] = (d > 0) ? 1.0f / (float)d : 0.0f;
    if (i == 0) indptr[0] = 0;
}

// invg from sorted-boundary gstart + identity-init of ac slot 0 (A=1, C=0)
__global__ __launch_bounds__(512) void invg_kernel(
    const int* __restrict__ gstart, float* __restrict__ invg,
    float* __restrict__ ac, int G)
{
    int g = threadIdx.x;
    if (g < G) {
        int c = gstart[g + 1] - gstart[g];
        invg[g] = (c > 0) ? 1.0f / (float)c : 0.0f;
    }
    if (g < 64) ac[g] = 1.0f;
    else if (g < 128) ac[g] = 0.0f;
}

__global__ __launch_bounds__(256) void csr_fill_kernel(
    const int2* __restrict__ pairs, const int* __restrict__ bktoff,
    const int* __restrict__ indptr, int* __restrict__ esrc, int N)
{
    __shared__ int cur[256];
    int j = blockIdx.x, t = threadIdx.x;
    int idx = j * 256 + t;
    cur[t] = (idx < N) ? indptr[idx] : 0;
    __syncthreads();
    int e0 = bktoff[j], e1 = bktoff[j + 1];
    for (int i = e0 + t; i < e1; i += 256) {
        int2 e = pairs[i];
        int p = atomicAdd(&cur[e.x & 255], 1);
        esrc[p] = e.y;
    }
}

// ---------- per-layer ----------
// agg: edge-index broadcast, explicit 16-deep gather batches (round-14 form).
// zout = A*(z_own + mean(z_nb)) + C*(1+[deg>0]); A,C from the ac slot.
__global__ __launch_bounds__(256) void agg_kernel(
    const float* __restrict__ zprev, const ushort_t* __restrict__ zb,
    const int* __restrict__ indptr, const int* __restrict__ esrc,
    const float* __restrict__ inv_deg, const float* __restrict__ ac,
    float* __restrict__ zout, int n)
{
    int t = threadIdx.x;
    int grp = t >> 4, l = t & 15;
    int lane = t & 63;
    int gl0 = lane & 48;
    int node = blockIdx.x * 16 + grp;
    if (node >= n) return;
    int e0 = indptr[node], e1 = indptr[node + 1];
    // hoisted independent loads: overlap with the gather loop
    float idg = inv_deg[node];
    float4 own = *(const float4*)(zprev + (size_t)node * 64 + l * 4);
    float4 A = *(const float4*)(ac + l * 4);
    float4 C = *(const float4*)(ac + 64 + l * 4);
    float a0 = 0.f, a1 = 0.f, a2 = 0.f, a3 = 0.f;
    const ushort_t* zbl = zb + l * 4;

    int base = e0;
    // full chunks: 16 gathers batched (issue loop separate from accumulate)
    for (; base + 16 <= e1; base += 16) {
        int myi = esrc[base + l];
        uint2 vv[16];
        #pragma unroll
        for (int j = 0; j < 16; ++j) {
            int s = __shfl(myi, gl0 + j, 64);
            vv[j] = *(const uint2*)(zbl + (size_t)s * 64);
        }
        #pragma unroll
        for (int j = 0; j < 16; ++j) {
            a0 += __uint_as_float(vv[j].x << 16);
            a1 += __uint_as_float(vv[j].x & 0xffff0000u);
            a2 += __uint_as_float(vv[j].y << 16);
            a3 += __uint_as_float(vv[j].y & 0xffff0000u);
        }
    }
    // remainder: masked 16-wide batch; pad lanes re-read edge-0's row (L1 hit)
    // and are forced to +0.0f => accumulation chain is bit-identical.
    int cnt = e1 - base;
    if (cnt > 0) {
        int myi = (l < cnt) ? esrc[base + l] : 0;
        uint2 vv[16];
        #pragma unroll
        for (int j = 0; j < 16; ++j) {
            int jj = (j < cnt) ? j : 0;
            int s = __shfl(myi, gl0 + jj, 64);
            uint2 v = *(const uint2*)(zbl + (size_t)s * 64);
            vv[j].x = (j < cnt) ? v.x : 0u;
            vv[j].y = (j < cnt) ? v.y : 0u;
        }
        #pragma unroll
        for (int j = 0; j < 16; ++j) {
            a0 += __uint_as_float(vv[j].x << 16);
            a1 += __uint_as_float(vv[j].x & 0xffff0000u);
            a2 += __uint_as_float(vv[j].y << 16);
            a3 += __uint_as_float(vv[j].y & 0xffff0000u);
        }
    }

    float cf = (idg > 0.f) ? 2.f : 1.f;
    float4 r;
    r.x = fmaf(A.x, fmaf(idg, a0, own.x), C.x * cf);
    r.y = fmaf(A.y, fmaf(idg, a1, own.y), C.y * cf);
    r.z = fmaf(A.z, fmaf(idg, a2, own.z), C.z * cf);
    r.w = fmaf(A.w, fmaf(idg, a3, own.w), C.w * cf);
    *(float4*)(zout + (size_t)node * 64 + l * 4) = r;
}

// MLP: round-16 exact. 4 lanes/node, 16 features each, LDS weights, shfl
// broadcast, butterfly stats -> per-wave partial stores (no atomics).
__global__ __launch_bounds__(256, 2) void mlp_kernel(
    float* __restrict__ zf, ushort_t* __restrict__ zb,
    const float* __restrict__ W1f, const float* __restrict__ b1f,
    const float* __restrict__ W2f, const float* __restrict__ b2f,
    float* __restrict__ partials, int n)
{
    __shared__ float w1s[4096];
    __shared__ float w2s[4096];
    __shared__ float bs[128];
    int t = threadIdx.x;
    for (int i = t; i < 4096; i += 256) {
        w1s[i] = W1f[i];
        w2s[i] = W2f[i];
    }
    if (t < 64) bs[t] = b1f[t];
    else if (t < 128) bs[t] = b2f[t - 64];
    __syncthreads();

    int idx = blockIdx.x * 256 + t;
    int node = idx >> 2;
    bool valid = node < n;          // no early return: all lanes join the butterfly
    int sub = t & 3;
    int lane = t & 63;
    int grp = lane & ~3;          // base lane of my 4-lane group
    int j0 = sub * 16;
    float* zrow = zf + (size_t)node * 64;
    ushort_t* zbrow = zb + (size_t)node * 64;

    // my quarter of z
    float zc[16];
    if (valid) {
        const float4* zp = (const float4*)(zrow + j0);
        #pragma unroll
        for (int q = 0; q < 4; ++q) {
            float4 v = zp[q];
            zc[4*q] = v.x; zc[4*q+1] = v.y; zc[4*q+2] = v.z; zc[4*q+3] = v.w;
        }
    } else {
        #pragma unroll
        for (int q = 0; q < 16; ++q) zc[q] = 0.f;
    }

    // GEMM1: y[j0..j0+16)
    float y[16];
    #pragma unroll
    for (int q = 0; q < 16; ++q) y[q] = bs[j0 + q];
    #pragma unroll
    for (int k = 0; k < 64; ++k) {
        float a = __shfl(zc[k & 15], grp + (k >> 4), 64);
        const float4* w = (const float4*)(w1s + k * 64 + j0);
        #pragma unroll
        for (int q = 0; q < 4; ++q) {
            float4 wv = w[q];
            y[4*q]   = fmaf(a, wv.x, y[4*q]);
            y[4*q+1] = fmaf(a, wv.y, y[4*q+1]);
            y[4*q+2] = fmaf(a, wv.z, y[4*q+2]);
            y[4*q+3] = fmaf(a, wv.w, y[4*q+3]);
        }
    }
    #pragma unroll
    for (int q = 0; q < 16; ++q) y[q] = fmaxf(y[q], 0.f);

    // GEMM2: o[j0..j0+16)
    float o[16];
    #pragma unroll
    for (int q = 0; q < 16; ++q) o[q] = bs[64 + j0 + q];
    #pragma unroll
    for (int k = 0; k < 64; ++k) {
        float a = __shfl(y[k & 15], grp + (k >> 4), 64);
        const float4* w = (const float4*)(w2s + k * 64 + j0);
        #pragma unroll
        for (int q = 0; q < 4; ++q) {
            float4 wv = w[q];
            o[4*q]   = fmaf(a, wv.x, o[4*q]);
            o[4*q+1] = fmaf(a, wv.y, o[4*q+1]);
            o[4*q+2] = fmaf(a, wv.z, o[4*q+2]);
            o[4*q+3] = fmaf(a, wv.w, o[4*q+3]);
        }
    }

    // outer relu
    float h[16];
    #pragma unroll
    for (int q = 0; q < 16; ++q) h[q] = fmaxf(o[q], 0.f);

    // store fp32 + bf16 mirror (group-contiguous)
    if (valid) {
        #pragma unroll
        for (int q = 0; q < 4; ++q) {
            float4 v;
            v.x = h[4*q]; v.y = h[4*q+1]; v.z = h[4*q+2]; v.w = h[4*q+3];
            *(float4*)(zrow + j0 + q * 4) = v;
            __hip_bfloat16 p0 = __float2bfloat16(v.x);
            __hip_bfloat16 p1 = __float2bfloat16(v.y);
            __hip_bfloat16 p2 = __float2bfloat16(v.z);
            __hip_bfloat16 p3 = __float2bfloat16(v.w);
            uint2 pw;
            pw.x = (uint_t)*(ushort_t*)&p0 | ((uint_t)*(ushort_t*)&p1 << 16);
            pw.y = (uint_t)*(ushort_t*)&p2 | ((uint_t)*(ushort_t*)&p3 << 16);
            *(uint2*)(zbrow + j0 + q * 4) = pw;
        }
    }

    // ---- fused BN stats: butterfly over the 16 lanes sharing sub ----
    float qs[16];
    #pragma unroll
    for (int q = 0; q < 16; ++q) {
        float hv = valid ? h[q] : 0.f;
        h[q] = hv;
        qs[q] = hv * hv;
    }
    #pragma unroll
    for (int m = 4; m <= 32; m <<= 1) {
        #pragma unroll
        for (int q = 0; q < 16; ++q) {
            h[q]  += __shfl_xor(h[q],  m, 64);
            qs[q] += __shfl_xor(qs[q], m, 64);
        }
    }
    // lanes 0..3 hold the per-wave sums for features j0..j0+15.
    if ((lane >> 2) == 0) {
        int wid = idx >> 6;   // global wave id, 0..NWAVE-1
        #pragma unroll
        for (int q = 0; q < 16; ++q) {
            partials[(size_t)(j0 + q) * NWAVE + wid]      = h[q];
            partials[(size_t)(64 + j0 + q) * NWAVE + wid] = qs[q];
        }
    }
}

// reduce per-wave partials -> BN affine (A,C) for this layer's ac slot.
__global__ __launch_bounds__(256) void redstats_kernel(
    const float* __restrict__ partials, const float* __restrict__ gammaf,
    const float* __restrict__ betaf, float* __restrict__ ac_out)
{
    __shared__ float s1[256], s2[256];
    int f = blockIdx.x;
    int t = threadIdx.x;
    const float* ph = partials + (size_t)f * NWAVE;
    const float* pq = partials + (size_t)(64 + f) * NWAVE;
    float a = 0.f, b = 0.f;
    for (int i = t; i < NWAVE; i += 256) { a += ph[i]; b += pq[i]; }
    s1[t] = a; s2[t] = b;
    __syncthreads();
    for (int off = 128; off > 0; off >>= 1) {
        if (t < off) { s1[t] += s1[t + off]; s2[t] += s2[t + off]; }
        __syncthreads();
    }
    if (t == 0) {
        const float invN = 1.0f / (float)NN;
        float mu = s1[0] * invN;
        float var = s2[0] * invN - mu * mu;
        if (var < 0.f) var = 0.f;
        float A = gammaf[f] * rsqrtf(var + 1e-5f);
        float C = betaf[f] - mu * A;
        ac_out[f] = A;
        ac_out[64 + f] = C;
    }
}

// pools: h = A*z + C; node_pool (+=) or (l==3) direct write to out;
// gpool run-length atomics. (round-20 form, verified correct)
__global__ __launch_bounds__(256) void pool_kernel(
    const float* __restrict__ z, float* __restrict__ node_pool,
    const int* __restrict__ b32, const float* __restrict__ ac,
    float* __restrict__ gpool, const int* __restrict__ flags,
    void* __restrict__ out, int N, int first, int last)
{
    int wave = (blockIdx.x * 256 + threadIdx.x) >> 6;
    int f = threadIdx.x & 63;
    int n0 = wave * 16;
    if (n0 >= N) return;
    int n1 = min(n0 + 16, N);
    float A = ac[f], C = ac[64 + f];
    int fp32 = flags[0];
    float racc = 0.f;
    int cur = b32[n0];
    int n = n0;
    for (; n + 4 <= n1; n += 4) {
        int4 gv = *(const int4*)(b32 + n);
        size_t idx = (size_t)n * 64 + f;
        float z0 = z[idx];
        float z1 = z[idx + 64];
        float z2 = z[idx + 128];
        float z3 = z[idx + 192];
        float h0 = fmaf(z0, A, C);
        float h1 = fmaf(z1, A, C);
        float h2 = fmaf(z2, A, C);
        float h3 = fmaf(z3, A, C);
        float p0, p1, p2, p3;
        if (first) {
            p0 = h0; p1 = h1; p2 = h2; p3 = h3;
        } else {
            p0 = node_pool[idx]       + h0;
            p1 = node_pool[idx + 64]  + h1;
            p2 = node_pool[idx + 128] + h2;
            p3 = node_pool[idx + 192] + h3;
        }
        if (last) {
            if (fp32) {
                ((float*)out)[idx]       = p0;
                ((float*)out)[idx + 64]  = p1;
                ((float*)out)[idx + 128] = p2;
                ((float*)out)[idx + 192] = p3;
            } else {
                __hip_bfloat16 b0 = __float2bfloat16(p0);
                __hip_bfloat16 b1 = __float2bfloat16(p1);
                __hip_bfloat16 b2 = __float2bfloat16(p2);
                __hip_bfloat16 b3 = __float2bfloat16(p3);
                ((__hip_bfloat16*)out)[idx]       = b0;
                ((__hip_bfloat16*)out)[idx + 64]  = b1;
                ((__hip_bfloat16*)out)[idx + 128] = b2;
                ((__hip_bfloat16*)out)[idx + 192] = b3;
            }
        } else {
            node_pool[idx]       = p0;
            node_pool[idx + 64]  = p1;
            node_pool[idx + 128] = p2;
            node_pool[idx + 192] = p3;
        }
        int gs0 = gv.x, gs1 = gv.y, gs2 = gv.z, gs3 = gv.w;
        if (gs0 != cur) { atomicAdd(&gpool[(size_t)cur * 64 + f], racc); racc = 0.f; cur = gs0; }
        racc += h0;
        if (gs1 != cur) { atomicAdd(&gpool[(size_t)cur * 64 + f], racc); racc = 0.f; cur = gs1; }
        racc += h1;
        if (gs2 != cur) { atomicAdd(&gpool[(size_t)cur * 64 + f], racc); racc = 0.f; cur = gs2; }
        racc += h2;
        if (gs3 != cur) { atomicAdd(&gpool[(size_t)cur * 64 + f], racc); racc = 0.f; cur = gs3; }
        racc += h3;
    }
    for (; n < n1; ++n) {  // tail (unused when 16 | N; kept for safety)
        int g = b32[n];
        if (g != cur) { atomicAdd(&gpool[(size_t)cur * 64 + f], racc); racc = 0.f; cur = g; }
        size_t idx = (size_t)n * 64 + f;
        float hv = fmaf(z[idx], A, C);
        float np = first ? hv : (node_pool[idx] + hv);
        if (last) {
            if (fp32) ((float*)out)[idx] = np;
            else ((__hip_bfloat16*)out)[idx] = __float2bfloat16(np);
        } else node_pool[idx] = np;
        racc += hv;
    }
    atomicAdd(&gpool[(size_t)cur * 64 + f], racc);
}

// finalize: gpool tail only (node section written by pool l==3)
__global__ __launch_bounds__(256) void finalize_kernel(
    const float* __restrict__ gpool, const float* __restrict__ invg,
    const int* __restrict__ flags, void* __restrict__ out, int N)
{
    int i = blockIdx.x * 256 + threadIdx.x;
    if (i >= GG * 64) return;
    float v = gpool[i] * invg[i >> 6];
    int nd = N * 64;
    if (flags[0]) ((float*)out)[nd + i] = v;
    else ((__hip_bfloat16*)out)[nd + i] = __float2bfloat16(v);
}

extern "C" void kernel_launch(void* const* d_in, const int* in_sizes, int n_in,
                              void* d_out, int out_size, void* d_ws, size_t ws_size,
                              hipStream_t stream)
{
    constexpr int N = NN, E = EE, G = GG;
    constexpr int ND = N * 64;

    const void* x     = d_in[0];
    const void* W1    = d_in[1];
    const void* b1    = d_in[2];
    const void* W2    = d_in[3];
    const void* b2    = d_in[4];
    const void* gamma = d_in[5];
    const void* beta  = d_in[6];
    const int* ei     = (const int*)d_in[7];
    const int* batw   = (const int*)d_in[8];

    char* p = (char*)d_ws;
    auto alloc = [&](size_t bytes) -> char* {
        char* r = p;
        p += (bytes + 255) & ~(size_t)255;
        return r;
    };
    float*    zbufA     = (float*)alloc((size_t)ND * 4);
    float*    zbufB     = (float*)alloc((size_t)ND * 4);
    float*    node_pool = (float*)alloc((size_t)ND * 4);
    ushort_t* zb        = (ushort_t*)alloc((size_t)ND * 2);
    int*      esrc      = (int*)alloc((size_t)E * 4);
    int*      indptr    = (int*)alloc((size_t)(N + 1) * 4);
    int*      deg       = (int*)alloc((size_t)N * 4);
    int*      part      = (int*)alloc((size_t)N * 4);
    float*    invdeg    = (float*)alloc((size_t)N * 4);
    int*      b32       = (int*)alloc((size_t)N * 4);
    int*      bsum      = (int*)alloc(128 * 4);
    int*      gstart    = (int*)alloc((size_t)(G + 1) * 4);
    float*    invg      = (float*)alloc(G * 4);
    float*    gpool     = (float*)alloc((size_t)G * 64 * 4);
    float*    ac5       = (float*)alloc(5 * 128 * 4);  // slot0 identity, slots1..4 BN_l
    float*    partials  = (float*)alloc((size_t)128 * NWAVE * 4);  // 3.2 MB
    float*    wf        = (float*)alloc(33792 * 4);
    int*      flags     = (int*)alloc(16 * 4);
    int*      histo     = (int*)alloc((size_t)NBK * NHB * 4);
    int*      tot       = (int*)alloc((size_t)NBK * 4);
    int*      bktoff    = (int*)alloc((size_t)(NBK + 1) * 4);
    // pairs aliases node_pool: dead until first pool_kernel; E*8 == ND*4 bytes
    int2*     pairs     = (int2*)node_pool;

    hipMemsetAsync(gpool, 0, (size_t)G * 64 * 4, stream);

    detect_kernel<<<1, 256, 0, stream>>>(
        (const uint_t*)x, (const uint_t*)ei, (const uint_t*)batw, flags);
    cvt_w_kernel<<<132, 256, 0, stream>>>(W1, b1, W2, b2, gamma, beta, flags, wf);
    cvt_x_kernel<<<(ND + 255) / 256, 256, 0, stream>>>(x, flags, zbufA, zb, ND);
    cvt_batch_kernel<<<(N + 255) / 256, 256, 0, stream>>>(batw, flags, b32, gstart, N);
    count_hist_kernel<<<NHB, 256, 0, stream>>>(ei, flags, histo, E);
    blockscan_kernel<<<NBK, NHB, 0, stream>>>(histo, tot);
    bscan_kernel<<<1, 512, 0, stream>>>(tot, bktoff);
    pair_scatter_kernel<<<NHB, 256, 0, stream>>>(ei, flags, histo, bktoff, pairs, E);
    bucket_deg_kernel<<<NBK, 256, 0, stream>>>(pairs, bktoff, deg, N);
    int nb = (N + 1023) / 1024;  // 98
    scan1_kernel<<<nb, 256, 0, stream>>>(deg, part, bsum, N);
    scan2_kernel<<<1, 128, 0, stream>>>(bsum, nb);
    scan3_kernel<<<(N + 255) / 256, 256, 0, stream>>>(part, bsum, deg, indptr, invdeg, N);
    invg_kernel<<<1, 512, 0, stream>>>(gstart, invg, ac5, G);
    csr_fill_kernel<<<NBK, 256, 0, stream>>>(pairs, bktoff, indptr, esrc, N);

    float* zin = zbufA;
    float* zout = zbufB;
    for (int l = 0; l < 4; ++l) {
        agg_kernel<<<(N + 15) / 16, 256, 0, stream>>>(
            zin, zb, indptr, esrc, invdeg, ac5 + l * 128, zout, N);
        mlp_kernel<<<MLPGRID, 256, 0, stream>>>(
            zout, zb, wf + l * 4096, wf + 32768 + l * 64,
            wf + 16384 + l * 4096, wf + 33024 + l * 64,
            partials, N);
        redstats_kernel<<<64, 256, 0, stream>>>(
            partials, wf + 33280 + l * 64, wf + 33536 + l * 64,
            ac5 + (l + 1) * 128);
        pool_kernel<<<(N + 63) / 64, 256, 0, stream>>>(
            zout, node_pool, b32, ac5 + (l + 1) * 128, gpool, flags, d_out,
            N, (l == 0) ? 1 : 0, (l == 3) ? 1 : 0);
        float* tmp = zin; zin = zout; zout = tmp;
    }
    finalize_kernel<<<128, 256, 0, stream>>>(gpool, invg, flags, d_out, N);
}

// Round 13
// 600.348 us; speedup vs baseline: 3.9232x; 1.2750x over previous
//
#include <hip/hip_runtime.h>
#include <hip/hip_bf16.h>

// GIN_34789235098229 — round 22: MFMA mlp with split-bf16 (hi/lo) precision.
// Round 21 = 765.4us; mlp 4x97us = 51% of runtime. All 4 failed mlp rewrites
// shared one mechanism: >~50 live scalars/thread -> scratch spill. MFMA avoids
// it: fragments are collective (A/B 4 VGPR, acc 16 VGPR, all static indices).
// Accuracy: every tensor is (hi,lo) bf16 pairs, lo = bf16(v - f32(hi)); each
// product = 3 MFMAs (ah*bh + ah*bl + al*bh) => ~1e-5 rel error (fp32-grade),
// absmax stays 0.125. z flows as (zh,zl) ushort pairs (same bytes as fp32);
// gather still reads zh only (precision unchanged); zf fp32 buffer DELETED
// (pool reconstructs hi+lo). cvt_w prepacks W1/W2 hi/lo in B-fragment order.
// mlp: GEMM1 -> LDS (stride-68, 16B-aligned) -> GEMM2 -> stats butterfly
// (strides 16/32) -> coalesced stores. 32 nodes/wave, 96 MFMA, ~70 VGPR.

typedef unsigned short ushort_t;
typedef unsigned int uint_t;
typedef __attribute__((ext_vector_type(8))) short bf16x8;
typedef __attribute__((ext_vector_type(4))) float f32x4;

#define NN 100000
#define EE 3200000
#define GG 512
#define NBK 391    // ceil(NN/256); bucket = node >> 8
#define NHB 256    // histogram blocks
#define ECHUNK 12500  // EE / NHB exactly
#define MLPBLOCKS 782        // ceil(NN / 128 nodes-per-block)
#define NWAVE (MLPBLOCKS * 4)  // 3128 wave slots for stats partials
#define YSTRIDE 68   // LDS row stride in uints: 272B = 17x16B (aligned, low-conflict)

// ---------- detection ----------
__global__ __launch_bounds__(256) void detect_kernel(
    const uint_t* __restrict__ xw, const uint_t* __restrict__ ew,
    const uint_t* __restrict__ bw, int* __restrict__ flags)
{
    __shared__ int sb[256], se[256], sbb[256];
    int t = threadIdx.x;
    uint_t w = xw[t];
    uint_t eL = (w >> 7) & 0xffu;
    sb[t] = (eL >= 112u && eL <= 135u) ? 1 : 0;
    se[t] = (ew[2 * t + 1] == 0u) ? 1 : 0;
    sbb[t] = (bw[NN - 512 + 2 * t + 1] == 0u) ? 1 : 0;
    __syncthreads();
    for (int off = 128; off > 0; off >>= 1) {
        if (t < off) { sb[t] += sb[t + off]; se[t] += se[t + off]; sbb[t] += sbb[t + off]; }
        __syncthreads();
    }
    if (t == 0) {
        flags[0] = (sb[0] < 128) ? 1 : 0;   // 1 => fp32 floats
        flags[1] = (se[0] >= 128) ? 1 : 0;  // 1 => int64 edges
        flags[2] = (sbb[0] >= 128) ? 1 : 0; // 1 => int64 batch
    }
}

// ---------- canonicalization ----------
// wp: packed MFMA B-fragments, per layer 16384 ushorts:
//   index ((g*2+p)*8 + t4*2 + s)*512 + lane*8 + e
//   k = s*32 + (lane>>4)*8 + e ; col = t4*16 + (lane&15); g=0:W1 g=1:W2; p=0:hi p=1:lo
// bb: per layer 256 floats: b1[64], b2[64], gamma[64], beta[64]
__global__ __launch_bounds__(256) void cvt_w_kernel(
    const void* __restrict__ W1, const void* __restrict__ b1,
    const void* __restrict__ W2, const void* __restrict__ b2,
    const void* __restrict__ g, const void* __restrict__ be,
    const int* __restrict__ flags, ushort_t* __restrict__ wp,
    float* __restrict__ bb)
{
    int i = blockIdx.x * 256 + threadIdx.x;
    int fp32 = flags[0];
    if (i < 65536) {
        int L = i >> 14;
        int r = i & 16383;
        int gg = r >> 13;
        int p = (r >> 12) & 1;
        int t4 = (r >> 10) & 3;
        int s = (r >> 9) & 1;
        int lane = (r >> 3) & 63;
        int e = r & 7;
        int k = s * 32 + (lane >> 4) * 8 + e;
        int col = t4 * 16 + (lane & 15);
        int src = L * 4096 + k * 64 + col;
        const void* W = gg ? W2 : W1;
        float v = fp32 ? ((const float*)W)[src]
                       : __bfloat162float(((const __hip_bfloat16*)W)[src]);
        __hip_bfloat16 hb = __float2bfloat16(v);
        ushort_t outv;
        if (p) {
            __hip_bfloat16 lb = __float2bfloat16(v - __bfloat162float(hb));
            outv = *(ushort_t*)&lb;
        } else {
            outv = *(ushort_t*)&hb;
        }
        wp[i] = outv;
    } else if (i < 66560) {
        int j = i - 65536;
        int L = j >> 8;
        int r = j & 255;
        int kind = r >> 6;
        int f = r & 63;
        const void* src = (kind == 0) ? b1 : (kind == 1) ? b2 : (kind == 2) ? g : be;
        int off = L * 64 + f;
        float v = fp32 ? ((const float*)src)[off]
                       : __bfloat162float(((const __hip_bfloat16*)src)[off]);
        bb[L * 256 + kind * 64 + f] = v;
    }
}

// x -> (hi, lo) bf16 pair
__global__ __launch_bounds__(256) void cvt_x_kernel(
    const void* __restrict__ x, const int* __restrict__ flags,
    ushort_t* __restrict__ zh, ushort_t* __restrict__ zl, int total)
{
    int i = blockIdx.x * 256 + threadIdx.x;
    if (i >= total) return;
    float v;
    if (flags[0]) v = ((const float*)x)[i];
    else {
        uint_t u = (uint_t)((const ushort_t*)x)[i] << 16;
        v = __uint_as_float(u);
    }
    __hip_bfloat16 hb = __float2bfloat16(v);
    __hip_bfloat16 lb = __float2bfloat16(v - __bfloat162float(hb));
    zh[i] = *(ushort_t*)&hb;
    zl[i] = *(ushort_t*)&lb;
}

// batch is SORTED: zero-atomic group offsets via boundary detection.
__global__ __launch_bounds__(256) void cvt_batch_kernel(
    const int* __restrict__ bw, const int* __restrict__ flags,
    int* __restrict__ b32, int* __restrict__ gstart, int n)
{
    int i = blockIdx.x * 256 + threadIdx.x;
    if (i >= n) return;
    int i64 = flags[2];
    int v = i64 ? bw[2 * i] : bw[i];
    b32[i] = v;
    int vn = (i + 1 < n) ? (i64 ? bw[2 * (i + 1)] : bw[i + 1]) : GG;
    if (i == 0) {
        for (int g = 0; g <= v; ++g) gstart[g] = 0;
    }
    if (vn != v) {
        for (int g = v + 1; g <= vn; ++g) gstart[g] = i + 1;
    }
}

// ---------- atomic-free CSR build (unchanged) ----------
__global__ __launch_bounds__(256) void count_hist_kernel(
    const int* __restrict__ ei, const int* __restrict__ flags,
    int* __restrict__ histo, int E)
{
    __shared__ int lh[NBK];
    int b = blockIdx.x, t = threadIdx.x;
    for (int j = t; j < NBK; j += 256) lh[j] = 0;
    __syncthreads();
    int i64 = flags[1];
    int e0 = b * ECHUNK, e1 = min(e0 + ECHUNK, E);
    for (int i = e0 + t; i < e1; i += 256) {
        int d = i64 ? ei[2 * (E + i)] : ei[E + i];
        atomicAdd(&lh[d >> 8], 1);
    }
    __syncthreads();
    for (int j = t; j < NBK; j += 256) histo[j * NHB + b] = lh[j];
}

__global__ __launch_bounds__(NHB) void blockscan_kernel(
    int* __restrict__ histo, int* __restrict__ tot)
{
    __shared__ int sd[NHB];
    int j = blockIdx.x, t = threadIdx.x;
    int v = histo[j * NHB + t];
    sd[t] = v;
    __syncthreads();
    #pragma unroll
    for (int off = 1; off < NHB; off <<= 1) {
        int add = (t >= off) ? sd[t - off] : 0;
        __syncthreads();
        sd[t] += add;
        __syncthreads();
    }
    histo[j * NHB + t] = sd[t] - v;
    if (t == NHB - 1) tot[j] = sd[NHB - 1];
}

__global__ __launch_bounds__(512) void bscan_kernel(
    const int* __restrict__ tot, int* __restrict__ bktoff)
{
    __shared__ int sd[512];
    int t = threadIdx.x;
    int v = (t < NBK) ? tot[t] : 0;
    sd[t] = v;
    __syncthreads();
    #pragma unroll
    for (int off = 1; off < 512; off <<= 1) {
        int add = (t >= off) ? sd[t - off] : 0;
        __syncthreads();
        sd[t] += add;
        __syncthreads();
    }
    if (t < NBK) bktoff[t] = sd[t] - v;
    if (t == 511) bktoff[NBK] = sd[511];
}

__global__ __launch_bounds__(256) void pair_scatter_kernel(
    const int* __restrict__ ei, const int* __restrict__ flags,
    const int* __restrict__ histo, const int* __restrict__ bktoff,
    int2* __restrict__ pairs, int E)
{
    __shared__ int cur[NBK];
    int b = blockIdx.x, t = threadIdx.x;
    for (int j = t; j < NBK; j += 256) cur[j] = histo[j * NHB + b] + bktoff[j];
    __syncthreads();
    int i64 = flags[1];
    int e0 = b * ECHUNK, e1 = min(e0 + ECHUNK, E);
    for (int i = e0 + t; i < e1; i += 256) {
        int d = i64 ? ei[2 * (E + i)] : ei[E + i];
        int s = i64 ? ei[2 * i]       : ei[i];
        int p = atomicAdd(&cur[d >> 8], 1);
        pairs[p] = make_int2(d, s);
    }
}

__global__ __launch_bounds__(256) void bucket_deg_kernel(
    const int2* __restrict__ pairs, const int* __restrict__ bktoff,
    int* __restrict__ deg, int N)
{
    __shared__ int cnt[256];
    int j = blockIdx.x, t = threadIdx.x;
    cnt[t] = 0;
    __syncthreads();
    int e0 = bktoff[j], e1 = bktoff[j + 1];
    for (int i = e0 + t; i < e1; i += 256)
        atomicAdd(&cnt[pairs[i].x & 255], 1);
    __syncthreads();
    int idx = j * 256 + t;
    if (idx < N) deg[idx] = cnt[t];
}

__global__ __launch_bounds__(256) void scan1_kernel(
    const int* __restrict__ deg, int* __restrict__ part, int* __restrict__ bsum, int n)
{
    __shared__ int sd[256];
    int t = threadIdx.x;
    int i0 = blockIdx.x * 1024 + t * 4;
    int v0 = 0, v1 = 0, v2 = 0, v3 = 0;
    if (i0 + 3 < n) {
        int4 v = *(const int4*)(deg + i0);
        v0 = v.x; v1 = v.y; v2 = v.z; v3 = v.w;
    } else if (i0 < n) {
        v0 = deg[i0];
        if (i0 + 1 < n) v1 = deg[i0 + 1];
        if (i0 + 2 < n) v2 = deg[i0 + 2];
    }
    int s = v0 + v1 + v2 + v3;
    sd[t] = s;
    __syncthreads();
    #pragma unroll
    for (int off = 1; off < 256; off <<= 1) {
        int add = (t >= off) ? sd[t - off] : 0;
        __syncthreads();
        sd[t] += add;
        __syncthreads();
    }
    int incl = sd[t];
    int e0 = incl - s;
    int p0 = e0 + v0, p1 = p0 + v1, p2 = p1 + v2, p3 = p2 + v3;
    if (i0 < n)     part[i0]     = p0;
    if (i0 + 1 < n) part[i0 + 1] = p1;
    if (i0 + 2 < n) part[i0 + 2] = p2;
    if (i0 + 3 < n) part[i0 + 3] = p3;
    if (t == 255) bsum[blockIdx.x] = incl;
}

__global__ __launch_bounds__(128) void scan2_kernel(int* __restrict__ bsum, int nb)
{
    __shared__ int sd[128];
    int t = threadIdx.x;
    int own = (t < nb) ? bsum[t] : 0;
    sd[t] = own;
    __syncthreads();
    #pragma unroll
    for (int off = 1; off < 128; off <<= 1) {
        int add = (t >= off) ? sd[t - off] : 0;
        __syncthreads();
        sd[t] += add;
        __syncthreads();
    }
    if (t < nb) bsum[t] = sd[t] - own;
}

__global__ __launch_bounds__(256) void scan3_kernel(
    const int* __restrict__ part, const int* __restrict__ bsum,
    const int* __restrict__ deg, int* __restrict__ indptr,
    float* __restrict__ inv_deg, int n)
{
    int i = blockIdx.x * 256 + threadIdx.x;
    if (i >= n) return;
    int val = part[i] + bsum[i >> 10];
    indptr[i + 1] = val;
    int d = deg[i];
    inv_deg[i] = (d > 0) ? 1.0f / (float)d : 0.0f;
    if (i == 0) indptr[0] = 0;
}

// invg from sorted-boundary gstart + identity-init of ac slot 0 (A=1, C=0)
__global__ __launch_bounds__(512) void invg_kernel(
    const int* __restrict__ gstart, float* __restrict__ invg,
    float* __restrict__ ac, int G)
{
    int g = threadIdx.x;
    if (g < G) {
        int c = gstart[g + 1] - gstart[g];
        invg[g] = (c > 0) ? 1.0f / (float)c : 0.0f;
    }
    if (g < 64) ac[g] = 1.0f;
    else if (g < 128) ac[g] = 0.0f;
}

__global__ __launch_bounds__(256) void csr_fill_kernel(
    const int2* __restrict__ pairs, const int* __restrict__ bktoff,
    const int* __restrict__ indptr, int* __restrict__ esrc, int N)
{
    __shared__ int cur[256];
    int j = blockIdx.x, t = threadIdx.x;
    int idx = j * 256 + t;
    cur[t] = (idx < N) ? indptr[idx] : 0;
    __syncthreads();
    int e0 = bktoff[j], e1 = bktoff[j + 1];
    for (int i = e0 + t; i < e1; i += 256) {
        int2 e = pairs[i];
        int p = atomicAdd(&cur[e.x & 255], 1);
        esrc[p] = e.y;
    }
}

// ---------- per-layer ----------
// agg: gather reads zh (hi only, same precision as before); own = hi+lo;
// output written as (hi, lo) bf16 pair. zout = A*(own + mean(nb)) + C*cf.
__global__ __launch_bounds__(256) void agg_kernel(
    const ushort_t* __restrict__ zh_prev, const ushort_t* __restrict__ zl_prev,
    const int* __restrict__ indptr, const int* __restrict__ esrc,
    const float* __restrict__ inv_deg, const float* __restrict__ ac,
    ushort_t* __restrict__ zh_out, ushort_t* __restrict__ zl_out, int n)
{
    int t = threadIdx.x;
    int grp = t >> 4, l = t & 15;
    int lane = t & 63;
    int gl0 = lane & 48;
    int node = blockIdx.x * 16 + grp;
    if (node >= n) return;
    int e0 = indptr[node], e1 = indptr[node + 1];
    float idg = inv_deg[node];
    // own = hi + lo
    uint2 uh = *(const uint2*)(zh_prev + (size_t)node * 64 + l * 4);
    uint2 ul = *(const uint2*)(zl_prev + (size_t)node * 64 + l * 4);
    float4 own;
    own.x = __uint_as_float(uh.x << 16) + __uint_as_float(ul.x << 16);
    own.y = __uint_as_float(uh.x & 0xffff0000u) + __uint_as_float(ul.x & 0xffff0000u);
    own.z = __uint_as_float(uh.y << 16) + __uint_as_float(ul.y << 16);
    own.w = __uint_as_float(uh.y & 0xffff0000u) + __uint_as_float(ul.y & 0xffff0000u);
    float4 A = *(const float4*)(ac + l * 4);
    float4 C = *(const float4*)(ac + 64 + l * 4);
    float a0 = 0.f, a1 = 0.f, a2 = 0.f, a3 = 0.f;
    const ushort_t* zbl = zh_prev + l * 4;

    int base = e0;
    for (; base + 16 <= e1; base += 16) {
        int myi = esrc[base + l];
        uint2 vv[16];
        #pragma unroll
        for (int j = 0; j < 16; ++j) {
            int s = __shfl(myi, gl0 + j, 64);
            vv[j] = *(const uint2*)(zbl + (size_t)s * 64);
        }
        #pragma unroll
        for (int j = 0; j < 16; ++j) {
            a0 += __uint_as_float(vv[j].x << 16);
            a1 += __uint_as_float(vv[j].x & 0xffff0000u);
            a2 += __uint_as_float(vv[j].y << 16);
            a3 += __uint_as_float(vv[j].y & 0xffff0000u);
        }
    }
    int cnt = e1 - base;
    if (cnt > 0) {
        int myi = (l < cnt) ? esrc[base + l] : 0;
        uint2 vv[16];
        #pragma unroll
        for (int j = 0; j < 16; ++j) {
            int jj = (j < cnt) ? j : 0;
            int s = __shfl(myi, gl0 + jj, 64);
            uint2 v = *(const uint2*)(zbl + (size_t)s * 64);
            vv[j].x = (j < cnt) ? v.x : 0u;
            vv[j].y = (j < cnt) ? v.y : 0u;
        }
        #pragma unroll
        for (int j = 0; j < 16; ++j) {
            a0 += __uint_as_float(vv[j].x << 16);
            a1 += __uint_as_float(vv[j].x & 0xffff0000u);
            a2 += __uint_as_float(vv[j].y << 16);
            a3 += __uint_as_float(vv[j].y & 0xffff0000u);
        }
    }

    float cf = (idg > 0.f) ? 2.f : 1.f;
    float4 r;
    r.x = fmaf(A.x, fmaf(idg, a0, own.x), C.x * cf);
    r.y = fmaf(A.y, fmaf(idg, a1, own.y), C.y * cf);
    r.z = fmaf(A.z, fmaf(idg, a2, own.z), C.z * cf);
    r.w = fmaf(A.w, fmaf(idg, a3, own.w), C.w * cf);
    // split hi/lo and store
    __hip_bfloat16 hx = __float2bfloat16(r.x);
    __hip_bfloat16 hy = __float2bfloat16(r.y);
    __hip_bfloat16 hz = __float2bfloat16(r.z);
    __hip_bfloat16 hw = __float2bfloat16(r.w);
    __hip_bfloat16 lx = __float2bfloat16(r.x - __bfloat162float(hx));
    __hip_bfloat16 ly = __float2bfloat16(r.y - __bfloat162float(hy));
    __hip_bfloat16 lz = __float2bfloat16(r.z - __bfloat162float(hz));
    __hip_bfloat16 lw = __float2bfloat16(r.w - __bfloat162float(hw));
    uint2 ph, pl;
    ph.x = (uint_t)*(ushort_t*)&hx | ((uint_t)*(ushort_t*)&hy << 16);
    ph.y = (uint_t)*(ushort_t*)&hz | ((uint_t)*(ushort_t*)&hw << 16);
    pl.x = (uint_t)*(ushort_t*)&lx | ((uint_t)*(ushort_t*)&ly << 16);
    pl.y = (uint_t)*(ushort_t*)&lz | ((uint_t)*(ushort_t*)&lw << 16);
    *(uint2*)(zh_out + (size_t)node * 64 + l * 4) = ph;
    *(uint2*)(zl_out + (size_t)node * 64 + l * 4) = pl;
}

// MLP round 22: MFMA 16x16x32 bf16, split hi/lo (3 mfma per product).
// Per wave: 32 nodes (2 M-tiles). GEMM1 -> LDS (packed yh|yl) -> GEMM2 ->
// stats butterfly (strides 16/32) -> h via LDS -> coalesced (zh,zl) stores.
__global__ __launch_bounds__(256) void mlp_kernel(
    const ushort_t* __restrict__ zh_in, const ushort_t* __restrict__ zl_in,
    const ushort_t* __restrict__ wp, const float* __restrict__ bb,
    ushort_t* __restrict__ zh_out, ushort_t* __restrict__ zl_out,
    float* __restrict__ partials, int n)
{
    __shared__ uint_t ylds[4 * 32 * YSTRIDE];
    int tid = threadIdx.x;
    int lane = tid & 63;
    int w = tid >> 6;
    int c = lane & 15, q = lane >> 4;
    int nb = blockIdx.x * 128 + w * 32;
    int wid = blockIdx.x * 4 + w;
    uint_t* my = ylds + w * 32 * YSTRIDE;

    // ---- GEMM1 ----
    #pragma unroll
    for (int mt = 0; mt < 2; ++mt) {
        int row = nb + mt * 16 + c;
        bool rv = row < n;
        bf16x8 ah0, ah1, al0, al1;
        if (rv) {
            const ushort_t* ph = zh_in + (size_t)row * 64 + q * 8;
            const ushort_t* pl = zl_in + (size_t)row * 64 + q * 8;
            ah0 = *(const bf16x8*)(ph);
            ah1 = *(const bf16x8*)(ph + 32);
            al0 = *(const bf16x8*)(pl);
            al1 = *(const bf16x8*)(pl + 32);
        } else {
            #pragma unroll
            for (int e = 0; e < 8; ++e) { ah0[e] = 0; ah1[e] = 0; al0[e] = 0; al1[e] = 0; }
        }
        f32x4 acc[4] = {{0.f,0.f,0.f,0.f},{0.f,0.f,0.f,0.f},{0.f,0.f,0.f,0.f},{0.f,0.f,0.f,0.f}};
        #pragma unroll
        for (int t4 = 0; t4 < 4; ++t4) {
            #pragma unroll
            for (int s = 0; s < 2; ++s) {
                bf16x8 bh = *(const bf16x8*)(wp + (size_t)((t4 * 2 + s) * 512) + lane * 8);
                bf16x8 bl = *(const bf16x8*)(wp + (size_t)((8 + t4 * 2 + s) * 512) + lane * 8);
                bf16x8 a_h = s ? ah1 : ah0;
                bf16x8 a_l = s ? al1 : al0;
                acc[t4] = __builtin_amdgcn_mfma_f32_16x16x32_bf16(a_l, bh, acc[t4], 0, 0, 0);
                acc[t4] = __builtin_amdgcn_mfma_f32_16x16x32_bf16(a_h, bl, acc[t4], 0, 0, 0);
                acc[t4] = __builtin_amdgcn_mfma_f32_16x16x32_bf16(a_h, bh, acc[t4], 0, 0, 0);
            }
        }
        #pragma unroll
        for (int t4 = 0; t4 < 4; ++t4) {
            float b = bb[t4 * 16 + c];
            #pragma unroll
            for (int r = 0; r < 4; ++r) {
                float y = fmaxf(acc[t4][r] + b, 0.f);
                __hip_bfloat16 hb = __float2bfloat16(y);
                __hip_bfloat16 lb = __float2bfloat16(y - __bfloat162float(hb));
                uint_t u = (uint_t)*(ushort_t*)&hb | ((uint_t)*(ushort_t*)&lb << 16);
                my[(mt * 16 + q * 4 + r) * YSTRIDE + t4 * 16 + c] = u;
            }
        }
    }
    __syncthreads();

    // ---- GEMM2 ----
    float ssum[4] = {0.f, 0.f, 0.f, 0.f};
    float ssq[4] = {0.f, 0.f, 0.f, 0.f};
    #pragma unroll
    for (int mt = 0; mt < 2; ++mt) {
        int nl = mt * 16 + c;
        bf16x8 yah[2], yal[2];
        #pragma unroll
        for (int s = 0; s < 2; ++s) {
            const uint_t* pa = my + nl * YSTRIDE + s * 32 + q * 8;
            uint4 ua = *(const uint4*)(pa);
            uint4 ub = *(const uint4*)(pa + 4);
            yah[s][0] = (short)(ua.x & 0xffffu); yal[s][0] = (short)(ua.x >> 16);
            yah[s][1] = (short)(ua.y & 0xffffu); yal[s][1] = (short)(ua.y >> 16);
            yah[s][2] = (short)(ua.z & 0xffffu); yal[s][2] = (short)(ua.z >> 16);
            yah[s][3] = (short)(ua.w & 0xffffu); yal[s][3] = (short)(ua.w >> 16);
            yah[s][4] = (short)(ub.x & 0xffffu); yal[s][4] = (short)(ub.x >> 16);
            yah[s][5] = (short)(ub.y & 0xffffu); yal[s][5] = (short)(ub.y >> 16);
            yah[s][6] = (short)(ub.z & 0xffffu); yal[s][6] = (short)(ub.z >> 16);
            yah[s][7] = (short)(ub.w & 0xffffu); yal[s][7] = (short)(ub.w >> 16);
        }
        f32x4 acc[4] = {{0.f,0.f,0.f,0.f},{0.f,0.f,0.f,0.f},{0.f,0.f,0.f,0.f},{0.f,0.f,0.f,0.f}};
        #pragma unroll
        for (int t4 = 0; t4 < 4; ++t4) {
            #pragma unroll
            for (int s = 0; s < 2; ++s) {
                bf16x8 bh = *(const bf16x8*)(wp + (size_t)((16 + t4 * 2 + s) * 512) + lane * 8);
                bf16x8 bl = *(const bf16x8*)(wp + (size_t)((24 + t4 * 2 + s) * 512) + lane * 8);
                acc[t4] = __builtin_amdgcn_mfma_f32_16x16x32_bf16(yal[s], bh, acc[t4], 0, 0, 0);
                acc[t4] = __builtin_amdgcn_mfma_f32_16x16x32_bf16(yah[s], bl, acc[t4], 0, 0, 0);
                acc[t4] = __builtin_amdgcn_mfma_f32_16x16x32_bf16(yah[s], bh, acc[t4], 0, 0, 0);
            }
        }
        #pragma unroll
        for (int t4 = 0; t4 < 4; ++t4) {
            float b = bb[64 + t4 * 16 + c];
            #pragma unroll
            for (int r = 0; r < 4; ++r) {
                int node = nb + mt * 16 + q * 4 + r;
                float h = fmaxf(acc[t4][r] + b, 0.f);
                float hv = (node < n) ? h : 0.f;
                ssum[t4] += hv;
                ssq[t4] += hv * hv;
                my[(mt * 16 + q * 4 + r) * YSTRIDE + t4 * 16 + c] = __float_as_uint(h);
            }
        }
    }
    __syncthreads();

    // stats butterfly across the 4 quadrants (rows); lanes 0..15 store
    #pragma unroll
    for (int t4 = 0; t4 < 4; ++t4) {
        ssum[t4] += __shfl_xor(ssum[t4], 16, 64);
        ssum[t4] += __shfl_xor(ssum[t4], 32, 64);
        ssq[t4]  += __shfl_xor(ssq[t4], 16, 64);
        ssq[t4]  += __shfl_xor(ssq[t4], 32, 64);
    }
    if (lane < 16) {
        #pragma unroll
        for (int t4 = 0; t4 < 4; ++t4) {
            partials[(size_t)(t4 * 16 + lane) * NWAVE + wid] = ssum[t4];
            partials[(size_t)(64 + t4 * 16 + lane) * NWAVE + wid] = ssq[t4];
        }
    }

    // store phase: coalesced (zh, zl) from LDS h
    #pragma unroll
    for (int cc = 0; cc < 8; ++cc) {
        int li = lane + 64 * cc;
        int nl = li >> 4, fg = li & 15;
        int node = nb + nl;
        if (node < n) {
            uint4 u = *(const uint4*)(my + nl * YSTRIDE + fg * 4);
            float f0 = __uint_as_float(u.x);
            float f1 = __uint_as_float(u.y);
            float f2 = __uint_as_float(u.z);
            float f3 = __uint_as_float(u.w);
            __hip_bfloat16 h0 = __float2bfloat16(f0);
            __hip_bfloat16 h1 = __float2bfloat16(f1);
            __hip_bfloat16 h2 = __float2bfloat16(f2);
            __hip_bfloat16 h3 = __float2bfloat16(f3);
            __hip_bfloat16 l0 = __float2bfloat16(f0 - __bfloat162float(h0));
            __hip_bfloat16 l1 = __float2bfloat16(f1 - __bfloat162float(h1));
            __hip_bfloat16 l2 = __float2bfloat16(f2 - __bfloat162float(h2));
            __hip_bfloat16 l3 = __float2bfloat16(f3 - __bfloat162float(h3));
            uint2 ph, pl;
            ph.x = (uint_t)*(ushort_t*)&h0 | ((uint_t)*(ushort_t*)&h1 << 16);
            ph.y = (uint_t)*(ushort_t*)&h2 | ((uint_t)*(ushort_t*)&h3 << 16);
            pl.x = (uint_t)*(ushort_t*)&l0 | ((uint_t)*(ushort_t*)&l1 << 16);
            pl.y = (uint_t)*(ushort_t*)&l2 | ((uint_t)*(ushort_t*)&l3 << 16);
            *(uint2*)(zh_out + (size_t)node * 64 + fg * 4) = ph;
            *(uint2*)(zl_out + (size_t)node * 64 + fg * 4) = pl;
        }
    }
}

// reduce per-wave partials -> BN affine (A,C) for this layer's ac slot.
__global__ __launch_bounds__(256) void redstats_kernel(
    const float* __restrict__ partials, const float* __restrict__ gammaf,
    const float* __restrict__ betaf, float* __restrict__ ac_out)
{
    __shared__ float s1[256], s2[256];
    int f = blockIdx.x;
    int t = threadIdx.x;
    const float* ph = partials + (size_t)f * NWAVE;
    const float* pq = partials + (size_t)(64 + f) * NWAVE;
    float a = 0.f, b = 0.f;
    for (int i = t; i < NWAVE; i += 256) { a += ph[i]; b += pq[i]; }
    s1[t] = a; s2[t] = b;
    __syncthreads();
    for (int off = 128; off > 0; off >>= 1) {
        if (t < off) { s1[t] += s1[t + off]; s2[t] += s2[t + off]; }
        __syncthreads();
    }
    if (t == 0) {
        const float invN = 1.0f / (float)NN;
        float mu = s1[0] * invN;
        float var = s2[0] * invN - mu * mu;
        if (var < 0.f) var = 0.f;
        float A = gammaf[f] * rsqrtf(var + 1e-5f);
        float C = betaf[f] - mu * A;
        ac_out[f] = A;
        ac_out[64 + f] = C;
    }
}

// pools: z = hi+lo; h = A*z + C; node_pool (+=) or (l==3) direct write to out;
// gpool run-length atomics.
__global__ __launch_bounds__(256) void pool_kernel(
    const ushort_t* __restrict__ zh, const ushort_t* __restrict__ zl,
    float* __restrict__ node_pool, const int* __restrict__ b32,
    const float* __restrict__ ac, float* __restrict__ gpool,
    const int* __restrict__ flags, void* __restrict__ out,
    int N, int first, int last)
{
    int wave = (blockIdx.x * 256 + threadIdx.x) >> 6;
    int f = threadIdx.x & 63;
    int n0 = wave * 16;
    if (n0 >= N) return;
    int n1 = min(n0 + 16, N);
    float A = ac[f], C = ac[64 + f];
    int fp32 = flags[0];
    float racc = 0.f;
    int cur = b32[n0];
    int n = n0;
    for (; n + 4 <= n1; n += 4) {
        int4 gv = *(const int4*)(b32 + n);
        size_t idx = (size_t)n * 64 + f;
        float z0 = __uint_as_float((uint_t)zh[idx] << 16)       + __uint_as_float((uint_t)zl[idx] << 16);
        float z1 = __uint_as_float((uint_t)zh[idx + 64] << 16)  + __uint_as_float((uint_t)zl[idx + 64] << 16);
        float z2 = __uint_as_float((uint_t)zh[idx + 128] << 16) + __uint_as_float((uint_t)zl[idx + 128] << 16);
        float z3 = __uint_as_float((uint_t)zh[idx + 192] << 16) + __uint_as_float((uint_t)zl[idx + 192] << 16);
        float h0 = fmaf(z0, A, C);
        float h1 = fmaf(z1, A, C);
        float h2 = fmaf(z2, A, C);
        float h3 = fmaf(z3, A, C);
        float p0, p1, p2, p3;
        if (first) {
            p0 = h0; p1 = h1; p2 = h2; p3 = h3;
        } else {
            p0 = node_pool[idx]       + h0;
            p1 = node_pool[idx + 64]  + h1;
            p2 = node_pool[idx + 128] + h2;
            p3 = node_pool[idx + 192] + h3;
        }
        if (last) {
            if (fp32) {
                ((float*)out)[idx]       = p0;
                ((float*)out)[idx + 64]  = p1;
                ((float*)out)[idx + 128] = p2;
                ((float*)out)[idx + 192] = p3;
            } else {
                __hip_bfloat16 b0 = __float2bfloat16(p0);
                __hip_bfloat16 b1 = __float2bfloat16(p1);
                __hip_bfloat16 b2 = __float2bfloat16(p2);
                __hip_bfloat16 b3 = __float2bfloat16(p3);
                ((__hip_bfloat16*)out)[idx]       = b0;
                ((__hip_bfloat16*)out)[idx + 64]  = b1;
                ((__hip_bfloat16*)out)[idx + 128] = b2;
                ((__hip_bfloat16*)out)[idx + 192] = b3;
            }
        } else {
            node_pool[idx]       = p0;
            node_pool[idx + 64]  = p1;
            node_pool[idx + 128] = p2;
            node_pool[idx + 192] = p3;
        }
        int gs0 = gv.x, gs1 = gv.y, gs2 = gv.z, gs3 = gv.w;
        if (gs0 != cur) { atomicAdd(&gpool[(size_t)cur * 64 + f], racc); racc = 0.f; cur = gs0; }
        racc += h0;
        if (gs1 != cur) { atomicAdd(&gpool[(size_t)cur * 64 + f], racc); racc = 0.f; cur = gs1; }
        racc += h1;
        if (gs2 != cur) { atomicAdd(&gpool[(size_t)cur * 64 + f], racc); racc = 0.f; cur = gs2; }
        racc += h2;
        if (gs3 != cur) { atomicAdd(&gpool[(size_t)cur * 64 + f], racc); racc = 0.f; cur = gs3; }
        racc += h3;
    }
    for (; n < n1; ++n) {  // tail (unused when 16 | N; kept for safety)
        int g = b32[n];
        if (g != cur) { atomicAdd(&gpool[(size_t)cur * 64 + f], racc); racc = 0.f; cur = g; }
        size_t idx = (size_t)n * 64 + f;
        float zv = __uint_as_float((uint_t)zh[idx] << 16) + __uint_as_float((uint_t)zl[idx] << 16);
        float hv = fmaf(zv, A, C);
        float np = first ? hv : (node_pool[idx] + hv);
        if (last) {
            if (fp32) ((float*)out)[idx] = np;
            else ((__hip_bfloat16*)out)[idx] = __float2bfloat16(np);
        } else node_pool[idx] = np;
        racc += hv;
    }
    atomicAdd(&gpool[(size_t)cur * 64 + f], racc);
}

// finalize: gpool tail only (node section written by pool l==3)
__global__ __launch_bounds__(256) void finalize_kernel(
    const float* __restrict__ gpool, const float* __restrict__ invg,
    const int* __restrict__ flags, void* __restrict__ out, int N)
{
    int i = blockIdx.x * 256 + threadIdx.x;
    if (i >= GG * 64) return;
    float v = gpool[i] * invg[i >> 6];
    int nd = N * 64;
    if (flags[0]) ((float*)out)[nd + i] = v;
    else ((__hip_bfloat16*)out)[nd + i] = __float2bfloat16(v);
}

extern "C" void kernel_launch(void* const* d_in, const int* in_sizes, int n_in,
                              void* d_out, int out_size, void* d_ws, size_t ws_size,
                              hipStream_t stream)
{
    constexpr int N = NN, E = EE, G = GG;
    constexpr int ND = N * 64;

    const void* x     = d_in[0];
    const void* W1    = d_in[1];
    const void* b1    = d_in[2];
    const void* W2    = d_in[3];
    const void* b2    = d_in[4];
    const void* gamma = d_in[5];
    const void* beta  = d_in[6];
    const int* ei     = (const int*)d_in[7];
    const int* batw   = (const int*)d_in[8];

    char* p = (char*)d_ws;
    auto alloc = [&](size_t bytes) -> char* {
        char* r = p;
        p += (bytes + 255) & ~(size_t)255;
        return r;
    };
    ushort_t* zhA      = (ushort_t*)alloc((size_t)ND * 2);
    ushort_t* zlA      = (ushort_t*)alloc((size_t)ND * 2);
    ushort_t* zhB      = (ushort_t*)alloc((size_t)ND * 2);
    ushort_t* zlB      = (ushort_t*)alloc((size_t)ND * 2);
    float*    node_pool = (float*)alloc((size_t)ND * 4);
    int*      esrc      = (int*)alloc((size_t)E * 4);
    int*      indptr    = (int*)alloc((size_t)(N + 1) * 4);
    int*      deg       = (int*)alloc((size_t)N * 4);
    int*      part      = (int*)alloc((size_t)N * 4);
    float*    invdeg    = (float*)alloc((size_t)N * 4);
    int*      b32       = (int*)alloc((size_t)N * 4);
    int*      bsum      = (int*)alloc(128 * 4);
    int*      gstart    = (int*)alloc((size_t)(G + 1) * 4);
    float*    invg      = (float*)alloc(G * 4);
    float*    gpool     = (float*)alloc((size_t)G * 64 * 4);
    float*    ac5       = (float*)alloc(5 * 128 * 4);  // slot0 identity, slots1..4 BN_l
    float*    partials  = (float*)alloc((size_t)128 * NWAVE * 4);  // 1.6 MB
    ushort_t* wp        = (ushort_t*)alloc((size_t)4 * 16384 * 2); // packed weights
    float*    bb        = (float*)alloc(4 * 256 * 4);  // b1,b2,gamma,beta per layer
    int*      flags     = (int*)alloc(16 * 4);
    int*      histo     = (int*)alloc((size_t)NBK * NHB * 4);
    int*      tot       = (int*)alloc((size_t)NBK * 4);
    int*      bktoff    = (int*)alloc((size_t)(NBK + 1) * 4);
    // pairs aliases node_pool: dead until first pool_kernel; E*8 == ND*4 bytes
    int2*     pairs     = (int2*)node_pool;

    hipMemsetAsync(gpool, 0, (size_t)G * 64 * 4, stream);

    detect_kernel<<<1, 256, 0, stream>>>(
        (const uint_t*)x, (const uint_t*)ei, (const uint_t*)batw, flags);
    cvt_w_kernel<<<260, 256, 0, stream>>>(W1, b1, W2, b2, gamma, beta, flags, wp, bb);
    cvt_x_kernel<<<(ND + 255) / 256, 256, 0, stream>>>(x, flags, zhA, zlA, ND);
    cvt_batch_kernel<<<(N + 255) / 256, 256, 0, stream>>>(batw, flags, b32, gstart, N);
    count_hist_kernel<<<NHB, 256, 0, stream>>>(ei, flags, histo, E);
    blockscan_kernel<<<NBK, NHB, 0, stream>>>(histo, tot);
    bscan_kernel<<<1, 512, 0, stream>>>(tot, bktoff);
    pair_scatter_kernel<<<NHB, 256, 0, stream>>>(ei, flags, histo, bktoff, pairs, E);
    bucket_deg_kernel<<<NBK, 256, 0, stream>>>(pairs, bktoff, deg, N);
    int nb = (N + 1023) / 1024;  // 98
    scan1_kernel<<<nb, 256, 0, stream>>>(deg, part, bsum, N);
    scan2_kernel<<<1, 128, 0, stream>>>(bsum, nb);
    scan3_kernel<<<(N + 255) / 256, 256, 0, stream>>>(part, bsum, deg, indptr, invdeg, N);
    invg_kernel<<<1, 512, 0, stream>>>(gstart, invg, ac5, G);
    csr_fill_kernel<<<NBK, 256, 0, stream>>>(pairs, bktoff, indptr, esrc, N);

    for (int l = 0; l < 4; ++l) {
        agg_kernel<<<(N + 15) / 16, 256, 0, stream>>>(
            zhA, zlA, indptr, esrc, invdeg, ac5 + l * 128, zhB, zlB, N);
        mlp_kernel<<<MLPBLOCKS, 256, 0, stream>>>(
            zhB, zlB, wp + (size_t)l * 16384, bb + l * 256,
            zhA, zlA, partials, N);
        redstats_kernel<<<64, 256, 0, stream>>>(
            partials, bb + l * 256 + 128, bb + l * 256 + 192,
            ac5 + (l + 1) * 128);
        pool_kernel<<<(N + 63) / 64, 256, 0, stream>>>(
            zhA, zlA, node_pool, b32, ac5 + (l + 1) * 128, gpool, flags, d_out,
            N, (l == 0) ? 1 : 0, (l == 3) ? 1 : 0);
    }
    finalize_kernel<<<128, 256, 0, stream>>>(gpool, invg, flags, d_out, N);
}